// Round 11
// baseline (380.697 us; speedup 1.0000x reference)
//
#include <hip/hip_runtime.h>
#include <hip/hip_bf16.h>
#include <math.h>

// Problem constants (B=4, S=1024, D=1024, H=16, hd=64)
#define SEQ    1024
#define DMODEL 1024
#define NHEAD  16
#define HDIM   64
#define BATCH  4
#define MROWS  4096   // B*S

typedef float f32x4 __attribute__((ext_vector_type(4)));
typedef short s16x8 __attribute__((ext_vector_type(8)));
typedef _Float16 f16x8 __attribute__((ext_vector_type(8)));

__device__ __forceinline__ float bf2f(unsigned short u) {
    return __uint_as_float(((unsigned int)u) << 16);
}
__device__ __forceinline__ unsigned short f2bf(float f) {
    __hip_bfloat16 h = __float2bfloat16(f);   // RNE
    return *reinterpret_cast<unsigned short*>(&h);
}
// fp16 helpers (RNE)
__device__ __forceinline__ unsigned short f2h(float f) {
    _Float16 h = (_Float16)f;
    return *reinterpret_cast<unsigned short*>(&h);
}
__device__ __forceinline__ float h2f(unsigned short u) {
    _Float16 h = *reinterpret_cast<_Float16*>(&u);
    return (float)h;
}
// scaled fp16 split-2: x ~= h0 + h1 * 2^-11,  h1 stored PRE-SCALED by 2048
// so residuals stay in fp16 normal range. Representation error ~1.2e-7 |x|.
__device__ __forceinline__ void split2(float x, unsigned short& u0, unsigned short& u1) {
    u0 = f2h(x);
    float f0 = h2f(u0);
    u1 = f2h((x - f0) * 2048.0f);
}

// async global->LDS, 16B per lane, dest = wave-uniform base + lane*16
__device__ __forceinline__ void gload16(const void* g, void* l) {
    __builtin_amdgcn_global_load_lds(
        (const __attribute__((address_space(1))) unsigned int*)g,
        (__attribute__((address_space(3))) unsigned int*)l, 16, 0, 0);
}

// ---------------------------------------------------------------------------
// Input split: X[n] fp32 -> planes.
//   NS=1: single bf16 plane.   NS=2: fp16 split-2 planes (h1 pre-scaled 2048).
// DUAL: blockIdx.y selects (X0->P0) vs (X1->P1) -- Q and K in one dispatch.
// ---------------------------------------------------------------------------
template<int NS, bool DUAL>
__global__ __launch_bounds__(256) void splitx_k(const float* __restrict__ X0,
                                                unsigned short* __restrict__ P0,
                                                const float* __restrict__ X1,
                                                unsigned short* __restrict__ P1,
                                                int nvec, size_t plane)
{
    const float* X = X0;
    unsigned short* P = P0;
    if constexpr (DUAL) { if (blockIdx.y) { X = X1; P = P1; } }
    const int i = blockIdx.x * 256 + threadIdx.x;   // 8-element vector index
    if (i >= nvec) return;
    const float* src = X + (size_t)i * 8;
    float4 v0 = *(const float4*)src;
    float4 v1 = *(const float4*)(src + 4);
    float x[8] = {v0.x, v0.y, v0.z, v0.w, v1.x, v1.y, v1.z, v1.w};
    unsigned short p0[8], p1[8];
    #pragma unroll
    for (int e = 0; e < 8; ++e) {
        if (NS == 1) { p0[e] = f2bf(x[e]); }
        else         { split2(x[e], p0[e], p1[e]); }
    }
    *(uint4*)(P + (size_t)i * 8) = *(uint4*)p0;
    if (NS == 2) {
        *(uint4*)(P + plane + (size_t)i * 8) = *(uint4*)p1;
    }
}

// ---------------------------------------------------------------------------
// Weight split+transpose: W[K][N] fp32 -> NS planes Wt[p][N][K].
// DUAL: blockIdx.z selects (W0->Wt0) vs (W1->Wt1).
// ---------------------------------------------------------------------------
template<int NS, bool DUAL>
__global__ __launch_bounds__(256) void wsplit_k(const float* __restrict__ W0,
                                                unsigned short* __restrict__ Wt0,
                                                const float* __restrict__ W1,
                                                unsigned short* __restrict__ Wt1,
                                                size_t plane)
{
    const float* W = W0;
    unsigned short* Wt = Wt0;
    if constexpr (DUAL) { if (blockIdx.z) { W = W1; Wt = Wt1; } }
    __shared__ float tile[64][65];
    const int t  = threadIdx.x;
    const int n0 = blockIdx.x * 64;
    const int k0 = blockIdx.y * 64;
    const int col = t & 63;
    const int rq  = t >> 6;

    #pragma unroll
    for (int p = 0; p < 16; ++p) {
        const int row = p * 4 + rq;                      // k-local
        tile[row][col] = W[(size_t)(k0 + row) * DMODEL + n0 + col];
    }
    __syncthreads();
    #pragma unroll
    for (int p = 0; p < 16; ++p) {
        const int nrow = p * 4 + rq;                     // n-local
        const float v = tile[col][nrow];                 // = W[k0+col][n0+nrow]
        const size_t o = (size_t)(n0 + nrow) * DMODEL + k0 + col;
        if (NS == 1) {
            Wt[o] = f2bf(v);
        } else {
            unsigned short u0, u1;
            split2(v, u0, u1);
            Wt[o] = u0; Wt[plane + o] = u1;
        }
    }
}

// ---------------------------------------------------------------------------
// MFMA GEMM on pre-split planes: C = A @ W^T + bias.
// 256-thread blocks (4 waves), BM=128 BN=64 BK=32; each wave a 64x32 sub-tile
// (4x2 frags of 16x16). LDS S[2][NS][192][32] = 48KB (NS=2) / 24KB (NS=1).
// T4 counted-vmcnt pipeline (vmcnt(6)/vmcnt(3), 0 only on last K-step);
// sched_barrier(0) pins (rule #18); T5 setprio around MFMA cluster.
// DUAL (Q+K merged): blockIdx.z selects problem -> 1024 blocks, 3 blocks/CU.
//
// NS=2 (fp16 split-2) with NF=4 deferred fold: main term
//   zacc[f] = mfma(P0a, P0b, zacc[f])  -- chained in the MFMA's own f32
//   C-path (zero VALU), folded to fp64 every 4 K-steps (K=128).  Fold VALU
//   (64 f64-class ops/K-step, which exceeded the 24 MFMAs' cycles) drops 4x.
//   Added f32-chain rounding ~1e-7 rel -- below the scheme's dominant error
//   (dropped P1P1 ~2.4e-7) and ~100x below reference's own f32 fuzz.
// facc += P0a*P1b' + P1a'*P0b (2048-scaled, descaled 2^-11 at epilogue).
// ---------------------------------------------------------------------------
template<int NS, bool FOLD, bool SPLITOUT, bool DUAL>
__global__ __launch_bounds__(256, (NS == 1 ? 4 : 3))
void gemm_planes(const unsigned short* Ab0, const unsigned short* Bb0,
                 const float* bias0, float* __restrict__ Cp,
                 unsigned short* Pout0, float oscale0,
                 const unsigned short* Ab1, const unsigned short* Bb1,
                 const float* bias1, unsigned short* Pout1, float oscale1,
                 int M, int N, int K,
                 size_t planeA, size_t planeB, size_t planeO)
{
    const unsigned short* Ab = Ab0;
    const unsigned short* Bb = Bb0;
    const float* biasp = bias0;
    unsigned short* Pout = Pout0;
    float oscale = oscale0;
    if constexpr (DUAL) {
        if (blockIdx.z) { Ab = Ab1; Bb = Bb1; biasp = bias1; Pout = Pout1; oscale = oscale1; }
    }

    // rows 0..127 = A-tile, rows 128..191 = B-tile
    __shared__ unsigned short S[2][NS][192][32];

    const int t = threadIdx.x;
    const int w = t >> 6, l = t & 63, g = l >> 4, j = l & 15;
    const int wm = w >> 1;          // 0..1  (M direction, 64 rows each)
    const int wn = w & 1;           // 0..1  (N direction, 32 cols each)
    const int m0 = blockIdx.y * 128;
    const int n0 = blockIdx.x * 64;

    f32x4 facc[8];
    f32x4 zacc[8];
    #pragma unroll
    for (int f = 0; f < 8; ++f) {
        facc[f] = (f32x4){0.f, 0.f, 0.f, 0.f};
        zacc[f] = (f32x4){0.f, 0.f, 0.f, 0.f};
    }
    double dacc[8][4] = {};

    // staging geometry: wave w stages rows [w*16, w*16+16) of each 64-row
    // chunk; lane -> row l>>2, source col-granule (l&3) ^ ((l>>3)&3)
    // (pre-swizzled global source; LDS dest linear per gload_lds rule).
    const int stgrow = w * 16 + (l >> 2);
    const int stgcol = ((l & 3) ^ ((l >> 3) & 3)) * 8;
    const unsigned short* gA = Ab + (size_t)(m0 + stgrow) * K + stgcol;
    const unsigned short* gB = Bb + (size_t)(n0 + stgrow) * K + stgcol;

    auto stage = [&](int buf, int k0) {
        #pragma unroll
        for (int p = 0; p < NS; ++p) {
            gload16(gA + (size_t)p * planeA + k0,                  &S[buf][p][w * 16][0]);
            gload16(gA + (size_t)p * planeA + (size_t)64 * K + k0, &S[buf][p][64 + w * 16][0]);
            gload16(gB + (size_t)p * planeB + k0,                  &S[buf][p][128 + w * 16][0]);
        }
    };

    // swizzled fragment column (elements): matches the staging swizzle
    const int gs8 = (g ^ ((j >> 1) & 3)) * 8;

    stage(0, 0);
    const int NT = K / 32;
    for (int kt = 0; kt < NT; ++kt) {
        const int cur = kt & 1;
        if (kt + 1 < NT) {
            stage(cur ^ 1, (kt + 1) * 32);   // issue next tile: stays in flight
            if constexpr (NS == 2) asm volatile("s_waitcnt vmcnt(6)" ::: "memory");
            else                   asm volatile("s_waitcnt vmcnt(3)" ::: "memory");
        } else {
            asm volatile("s_waitcnt vmcnt(0)" ::: "memory");
        }
        __builtin_amdgcn_sched_barrier(0);
        __builtin_amdgcn_s_barrier();        // buf[cur] ready on all waves
        __builtin_amdgcn_sched_barrier(0);

        if constexpr (NS == 1) {
            s16x8 a[4];
            #pragma unroll
            for (int mi = 0; mi < 4; ++mi)
                a[mi] = *(const s16x8*)&S[cur][0][wm * 64 + mi * 16 + j][gs8];
            __builtin_amdgcn_s_setprio(1);
            #pragma unroll
            for (int ni = 0; ni < 2; ++ni) {
                const int nr = 128 + wn * 32 + ni * 16 + j;
                s16x8 b0 = *(const s16x8*)&S[cur][0][nr][gs8];
                #pragma unroll
                for (int mi = 0; mi < 4; ++mi) {
                    const int f = mi * 2 + ni;
                    facc[f] = __builtin_amdgcn_mfma_f32_16x16x32_bf16(a[mi], b0, facc[f], 0, 0, 0);
                }
            }
            __builtin_amdgcn_s_setprio(0);
        } else {
            f16x8 a0[4], a1[4];
            #pragma unroll
            for (int mi = 0; mi < 4; ++mi) {
                a0[mi] = *(const f16x8*)&S[cur][0][wm * 64 + mi * 16 + j][gs8];
                a1[mi] = *(const f16x8*)&S[cur][1][wm * 64 + mi * 16 + j][gs8];
            }
            __builtin_amdgcn_s_setprio(1);
            #pragma unroll
            for (int ni = 0; ni < 2; ++ni) {
                const int nr = 128 + wn * 32 + ni * 16 + j;
                f16x8 b0 = *(const f16x8*)&S[cur][0][nr][gs8];
                f16x8 b1 = *(const f16x8*)&S[cur][1][nr][gs8];
                #pragma unroll
                for (int mi = 0; mi < 4; ++mi) {
                    const int f = mi * 2 + ni;
                    zacc[f] = __builtin_amdgcn_mfma_f32_16x16x32_f16(a0[mi], b0, zacc[f], 0, 0, 0);
                    facc[f] = __builtin_amdgcn_mfma_f32_16x16x32_f16(a0[mi], b1, facc[f], 0, 0, 0);
                    facc[f] = __builtin_amdgcn_mfma_f32_16x16x32_f16(a1[mi], b0, facc[f], 0, 0, 0);
                }
            }
            __builtin_amdgcn_s_setprio(0);
            // NF=4 deferred fold: fp64 fold every 4 K-steps (NT=32 -> kt=31 hits)
            if ((kt & 3) == 3 || kt == NT - 1) {
                #pragma unroll
                for (int f = 0; f < 8; ++f) {
                    #pragma unroll
                    for (int r = 0; r < 4; ++r) dacc[f][r] += (double)zacc[f][r];
                    zacc[f] = (f32x4){0.f, 0.f, 0.f, 0.f};
                }
            }
        }

        __builtin_amdgcn_sched_barrier(0);
        __builtin_amdgcn_s_barrier();        // all reads of buf[cur] done
        __builtin_amdgcn_sched_barrier(0);
    }

    #pragma unroll
    for (int ni = 0; ni < 2; ++ni) {
        const int col = n0 + wn * 32 + ni * 16 + j;
        const float bv = biasp[col];
        #pragma unroll
        for (int mi = 0; mi < 4; ++mi) {
            const int f = mi * 2 + ni;
            #pragma unroll
            for (int r = 0; r < 4; ++r) {
                const int row = m0 + wm * 64 + mi * 16 + 4 * g + r;
                float val;
                if (FOLD) val = (float)(dacc[f][r] + (double)facc[f][r] * (1.0 / 2048.0) + (double)bv);
                else      val = facc[f][r] + bv;
                if (SPLITOUT) {
                    const int bq = row >> 10, s = row & 1023;
                    const int h  = col >> 6,  d = col & 63;
                    const size_t o = (((size_t)(bq * 16 + h)) * SEQ + s) * HDIM + d;
                    unsigned short u0, u1;
                    split2(val * oscale, u0, u1);
                    Pout[o] = u0; Pout[planeO + o] = u1;
                } else {
                    Cp[(size_t)row * N + col] = val;
                }
            }
        }
    }
}

// ---------------------------------------------------------------------------
// Fused attention, single-pass: 128 q-rows/block (8 waves, one 16-row q-tile
// per wave), K chunks staged in LDS and shared by all 8 waves.
// q3/k3 are fp16 split-2 planes:
//   score = accM + (accC0+accC1) * 2^-11   (6 MFMAs/kb)
// T14 async-STAGE split: chunk ch+1's global loads issued right after the
// stage barrier of ch, consumed at the next iteration's ds_write.
// Online (m,Z) + dead-exp wave-uniform skip; exact fp64-cut prune; sparse PV
// gather (4-wide load batching). LDS ~52 KB -> 2 blocks/CU; grid 512 = 2/CU.
// UNCHANGED from round 9 (clean per-dispatch attribution).
// ---------------------------------------------------------------------------
#define CAND 32
#define QROWS 128
__global__ __launch_bounds__(512, 4) void attn_k(const unsigned short* __restrict__ q3,
                                                 const unsigned short* __restrict__ k3,
                                                 const float* __restrict__ vf,
                                                 unsigned short* __restrict__ attnb,
                                                 size_t plane)
{
    __shared__ unsigned short Ks[2][64][72];   // 18.4 KB
    __shared__ int   ckey[QROWS][CAND];        // 16 KB
    __shared__ float csc[QROWS][CAND];         // 16 KB
    __shared__ int   ccnt[QROWS];
    __shared__ float zinv[QROWS];

    const int t  = threadIdx.x;
    const int w  = t >> 6, l = t & 63, g = l >> 4, j = l & 15;
    const int bh = blockIdx.x >> 3;     // 0..63
    const int qt = blockIdx.x & 7;      // 0..7 (128-row q groups)
    const int b  = bh >> 4, h = bh & 15;

    if (t < QROWS) ccnt[t] = 0;

    // A-frags for this wave's 16 q-rows (q pre-scaled 1/8 in planes)
    f16x8 aq[2][2];
    {
        const size_t qoff = ((size_t)bh * SEQ + qt * QROWS + w * 16 + j) * HDIM + g * 8;
        #pragma unroll
        for (int p = 0; p < 2; ++p)
            #pragma unroll
            for (int half = 0; half < 2; ++half)
                aq[p][half] = *(const f16x8*)(q3 + p * plane + qoff + half * 32);
    }

    // staging: 512 threads, each one uint4 (8 elems) per plane
    const int skey = t >> 3;            // staging key-local 0..63
    const int soff = (t & 7) * 8;       // element offset 0..56
    const unsigned short* ksrc = k3 + (size_t)bh * (SEQ * HDIM) + (size_t)skey * HDIM + soff;

    float rm[4], rz[4];
    #pragma unroll
    for (int r = 0; r < 4; ++r) { rm[r] = -INFINITY; rz[r] = 0.f; }

    // T14 prologue: chunk 0 loads in flight before the loop
    uint4 stg0 = *(const uint4*)(ksrc);
    uint4 stg1 = *(const uint4*)(ksrc + plane);

    for (int ch = 0; ch < 16; ++ch) {
        __syncthreads();                      // Ks free (prev readers done)
        *(uint4*)&Ks[0][skey][soff] = stg0;
        *(uint4*)&Ks[1][skey][soff] = stg1;
        __syncthreads();                      // Ks ready
        // issue next chunk's loads now; consumed at next iteration's ds_write
        if (ch + 1 < 16) {
            const unsigned short* s = ksrc + (ch + 1) * 4096;
            stg0 = *(const uint4*)(s);
            stg1 = *(const uint4*)(s + plane);
        }

        float sc[4][4];   // [kb][r]
        __builtin_amdgcn_s_setprio(1);
        #pragma unroll
        for (int kb = 0; kb < 4; ++kb) {
            f32x4 accM = {0.f,0.f,0.f,0.f};
            f32x4 accC0 = {0.f,0.f,0.f,0.f}, accC1 = {0.f,0.f,0.f,0.f};
            const int kr = kb * 16 + j;
            #pragma unroll
            for (int half = 0; half < 2; ++half) {
                f16x8 b0 = *(const f16x8*)&Ks[0][kr][half * 32 + g * 8];
                f16x8 b1 = *(const f16x8*)&Ks[1][kr][half * 32 + g * 8];
                accM  = __builtin_amdgcn_mfma_f32_16x16x32_f16(aq[0][half], b0, accM,  0, 0, 0);
                accC0 = __builtin_amdgcn_mfma_f32_16x16x32_f16(aq[0][half], b1, accC0, 0, 0, 0);
                accC1 = __builtin_amdgcn_mfma_f32_16x16x32_f16(aq[1][half], b0, accC1, 0, 0, 0);
            }
            #pragma unroll
            for (int r = 0; r < 4; ++r)
                sc[kb][r] = accM[r] + (accC0[r] + accC1[r]) * (1.0f / 2048.0f);
        }
        __builtin_amdgcn_s_setprio(0);

        // online (m,Z) with row-global running max + candidate capture
        #pragma unroll
        for (int r = 0; r < 4; ++r) {
            float nmc = fmaxf(fmaxf(sc[0][r], sc[1][r]), fmaxf(sc[2][r], sc[3][r]));
            #pragma unroll
            for (int off = 1; off < 16; off <<= 1) nmc = fmaxf(nmc, __shfl_xor(nmc, off));
            // dead-exp skip: all terms sub-half-ulp of rz and no candidate can
            // pass thr=rm-0.004 -> wave-uniform skip (no barrier inside).
            if (__all(nmc <= rm[r] - 0.03f)) continue;
            const float nm = fmaxf(nmc, rm[r]);
            float add = 0.f;
            #pragma unroll
            for (int kb = 0; kb < 4; ++kb) add += __expf((sc[kb][r] - nm) * 1000.f);
            rz[r] = rz[r] * __expf((rm[r] - nm) * 1000.f) + add;
            rm[r] = nm;
            const float thr = nm - 0.004f;   // cut >= m_final-0.00396 >= nm-0.00396
            #pragma unroll
            for (int kb = 0; kb < 4; ++kb) {
                if (sc[kb][r] >= thr) {
                    const int row = w * 16 + 4 * g + r;
                    const int pos = atomicAdd(&ccnt[row], 1);
                    if (pos < CAND) {
                        ckey[row][pos] = ch * 64 + kb * 16 + j;
                        csc[row][pos]  = sc[kb][r];
                    }
                }
            }
        }
    }
    __syncthreads();

    // finalize: Z reduce across 16 lanes, exact cut, prune+compact candidates
    float Zr[4];
    #pragma unroll
    for (int r = 0; r < 4; ++r) {
        float z = rz[r];
        #pragma unroll
        for (int off = 1; off < 16; off <<= 1) z += __shfl_xor(z, off);
        Zr[r] = z;
    }
    #pragma unroll
    for (int r = 0; r < 4; ++r) {
        if (j == r) {
            const int row = w * 16 + 4 * g + r;
            const double cut = (double)rm[r] + 0.001 * log(0.019 * (double)Zr[r]);
            const int craw = ccnt[row];
            const int c = craw < CAND ? craw : CAND;
            int n = 0; float z2 = 0.f;
            for (int i = 0; i < c; ++i) {
                const float s = csc[row][i];
                if ((double)s >= cut) {
                    const float ev = __expf(s - rm[r]);
                    ckey[row][n] = ckey[row][i];
                    csc[row][n]  = ev;
                    z2 += ev; ++n;
                }
            }
            ccnt[row] = (craw > CAND) ? -1 : n;   // -1 = overflow sentinel
            zinv[row] = (n > 0) ? 1.f / z2 : 0.f;
        }
    }
    __syncthreads();

    // sparse PV gather (wave w handles its own 16 rows; lane l = dim).
    // 4-way load batching; fmac order matches the serial loop.
    const float* vbase = vf + (size_t)b * SEQ * DMODEL + h * HDIM + l;
    for (int i = 0; i < 16; ++i) {
        const int row = w * 16 + i;
        const int n = ccnt[row];
        float o = 0.f;
        if (n == 0) {
            // all masked -> uniform weights over all 1024 keys
            for (int kk = 0; kk < SEQ; ++kk) o += vbase[(size_t)kk * DMODEL];
            o *= (1.0f / 1024.0f);
        } else if (n < 0) {
            o = INFINITY;   // candidate overflow sentinel (P ~ 1e-6)
        } else {
            const float inv = zinv[row];
            int i2 = 0;
            for (; i2 + 4 <= n; i2 += 4) {
                const float c0 = csc[row][i2 + 0], c1 = csc[row][i2 + 1];
                const float c2 = csc[row][i2 + 2], c3 = csc[row][i2 + 3];
                const float v0 = vbase[(size_t)ckey[row][i2 + 0] * DMODEL];
                const float v1 = vbase[(size_t)ckey[row][i2 + 1] * DMODEL];
                const float v2 = vbase[(size_t)ckey[row][i2 + 2] * DMODEL];
                const float v3 = vbase[(size_t)ckey[row][i2 + 3] * DMODEL];
                o += c0 * v0; o += c1 * v1; o += c2 * v2; o += c3 * v3;
            }
            for (; i2 < n; ++i2)
                o += csc[row][i2] * vbase[(size_t)ckey[row][i2] * DMODEL];
            o *= inv;
        }
        attnb[((size_t)b * SEQ + qt * QROWS + row) * DMODEL + h * HDIM + l] = f2bf(o);
    }
}

// ---------------------------------------------------------------------------
extern "C" void kernel_launch(void* const* d_in, const int* in_sizes, int n_in,
                              void* d_out, int out_size, void* d_ws, size_t ws_size,
                              hipStream_t stream) {
    const float* Q  = (const float*)d_in[0];
    const float* K  = (const float*)d_in[1];
    const float* V  = (const float*)d_in[2];
    const float* Wq = (const float*)d_in[3];
    const float* bq = (const float*)d_in[4];
    const float* Wk = (const float*)d_in[5];
    const float* bk = (const float*)d_in[6];
    const float* Wv = (const float*)d_in[7];
    const float* bv = (const float*)d_in[8];
    const float* Wo = (const float*)d_in[9];
    const float* bo = (const float*)d_in[10];

    const size_t PLANE  = (size_t)MROWS * DMODEL;     // 4 Mi elements
    const size_t WPLANE = (size_t)DMODEL * DMODEL;

    // Workspace layout (90 MiB total):
    unsigned short* R1 = (unsigned short*)d_ws;        // 2P: V split (1P) -> Q split -> attnb
    unsigned short* R2 = R1 + 2 * PLANE;               // 2P: K split
    unsigned short* W1 = R2 + 2 * PLANE;               // 1W: Wv, later Wo
    unsigned short* W2 = W1 + WPLANE;                  // 2W: Wq planes
    unsigned short* W3 = W2 + 2 * WPLANE;              // 2W: Wk planes
    unsigned short* q3 = W3 + 2 * WPLANE;              // 2P
    unsigned short* k3 = q3 + 2 * PLANE;               // 2P
    float*          vf = (float*)(k3 + 2 * PLANE);     // PLANE f32
    unsigned short* attnb = R1;                        // reuse after QK GEMM

    dim3 blk(256, 1, 1);
    const int nvec = (int)(PLANE / 8);
    dim3 gs((nvec + 255) / 256, 1, 1);
    dim3 gs2((nvec + 255) / 256, 2, 1);
    dim3 gw(DMODEL / 64, DMODEL / 64, 1);
    dim3 gw2(DMODEL / 64, DMODEL / 64, 2);
    dim3 gg(DMODEL / 64, MROWS / 128, 1);              // 512 blocks (NS=1)
    dim3 gg2(DMODEL / 64, MROWS / 128, 2);             // 1024 blocks (merged Q+K)

    // ---- V projection first (frees R1 for Q split) ----
    splitx_k<1, false><<<gs, blk, 0, stream>>>(V, R1, nullptr, nullptr, nvec, PLANE);
    wsplit_k<1, false><<<gw, blk, 0, stream>>>(Wv, W1, nullptr, nullptr, WPLANE);
    gemm_planes<1, false, false, false><<<gg, blk, 0, stream>>>(
        R1, W1, bv, vf, nullptr, 1.0f,
        nullptr, nullptr, nullptr, nullptr, 0.f,
        MROWS, DMODEL, DMODEL, PLANE, WPLANE, PLANE);

    // ---- Q+K splits and projections, merged dispatches ----
    splitx_k<2, true><<<gs2, blk, 0, stream>>>(Q, R1, K, R2, nvec, PLANE);
    wsplit_k<2, true><<<gw2, blk, 0, stream>>>(Wq, W2, Wk, W3, WPLANE);
    gemm_planes<2, true, true, true><<<gg2, blk, 0, stream>>>(
        R1, W2, bq, nullptr, q3, 0.125f,
        R2, W3, bk, k3, 1.0f,
        MROWS, DMODEL, DMODEL, PLANE, WPLANE, PLANE);

    // ---- fused masked attention (single pass) -> bf16 attnb ----
    attn_k<<<dim3(64 * 8, 1, 1), dim3(512, 1, 1), 0, stream>>>(q3, k3, vf, attnb, PLANE);

    // ---- O projection (plain bf16 MFMA) -> fp32 d_out ----
    wsplit_k<1, false><<<gw, blk, 0, stream>>>(Wo, W1, nullptr, nullptr, WPLANE);
    gemm_planes<1, false, false, false><<<gg, blk, 0, stream>>>(
        attnb, W1, bo, (float*)d_out, nullptr, 1.0f,
        nullptr, nullptr, nullptr, nullptr, 0.f,
        MROWS, DMODEL, DMODEL, PLANE, WPLANE, PLANE);
}

// Round 12
// 292.383 us; speedup vs baseline: 1.3020x; 1.3020x over previous
//
#include <hip/hip_runtime.h>
#include <hip/hip_bf16.h>
#include <math.h>

// Problem constants (B=4, S=1024, D=1024, H=16, hd=64)
#define SEQ    1024
#define DMODEL 1024
#define NHEAD  16
#define HDIM   64
#define BATCH  4
#define MROWS  4096   // B*S

typedef float f32x4 __attribute__((ext_vector_type(4)));
typedef short s16x8 __attribute__((ext_vector_type(8)));
typedef _Float16 f16x8 __attribute__((ext_vector_type(8)));

__device__ __forceinline__ float bf2f(unsigned short u) {
    return __uint_as_float(((unsigned int)u) << 16);
}
__device__ __forceinline__ unsigned short f2bf(float f) {
    __hip_bfloat16 h = __float2bfloat16(f);   // RNE
    return *reinterpret_cast<unsigned short*>(&h);
}
// fp16 helpers (RNE)
__device__ __forceinline__ unsigned short f2h(float f) {
    _Float16 h = (_Float16)f;
    return *reinterpret_cast<unsigned short*>(&h);
}
__device__ __forceinline__ float h2f(unsigned short u) {
    _Float16 h = *reinterpret_cast<_Float16*>(&u);
    return (float)h;
}
// scaled fp16 split-2: x ~= h0 + h1 * 2^-11,  h1 stored PRE-SCALED by 2048
// so residuals stay in fp16 normal range. Representation error ~1.2e-7 |x|.
__device__ __forceinline__ void split2(float x, unsigned short& u0, unsigned short& u1) {
    u0 = f2h(x);
    float f0 = h2f(u0);
    u1 = f2h((x - f0) * 2048.0f);
}

// async global->LDS, 16B per lane, dest = wave-uniform base + lane*16
__device__ __forceinline__ void gload16(const void* g, void* l) {
    __builtin_amdgcn_global_load_lds(
        (const __attribute__((address_space(1))) unsigned int*)g,
        (__attribute__((address_space(3))) unsigned int*)l, 16, 0, 0);
}

// ---------------------------------------------------------------------------
// Input split: X[n] fp32 -> planes.
//   NS=1: single bf16 plane.   NS=2: fp16 split-2 planes (h1 pre-scaled 2048).
// DUAL: blockIdx.y selects (X0->P0) vs (X1->P1) -- Q and K in one dispatch.
// ---------------------------------------------------------------------------
template<int NS, bool DUAL>
__global__ __launch_bounds__(256) void splitx_k(const float* __restrict__ X0,
                                                unsigned short* __restrict__ P0,
                                                const float* __restrict__ X1,
                                                unsigned short* __restrict__ P1,
                                                int nvec, size_t plane)
{
    const float* X = X0;
    unsigned short* P = P0;
    if constexpr (DUAL) { if (blockIdx.y) { X = X1; P = P1; } }
    const int i = blockIdx.x * 256 + threadIdx.x;   // 8-element vector index
    if (i >= nvec) return;
    const float* src = X + (size_t)i * 8;
    float4 v0 = *(const float4*)src;
    float4 v1 = *(const float4*)(src + 4);
    float x[8] = {v0.x, v0.y, v0.z, v0.w, v1.x, v1.y, v1.z, v1.w};
    unsigned short p0[8], p1[8];
    #pragma unroll
    for (int e = 0; e < 8; ++e) {
        if (NS == 1) { p0[e] = f2bf(x[e]); }
        else         { split2(x[e], p0[e], p1[e]); }
    }
    *(uint4*)(P + (size_t)i * 8) = *(uint4*)p0;
    if (NS == 2) {
        *(uint4*)(P + plane + (size_t)i * 8) = *(uint4*)p1;
    }
}

// ---------------------------------------------------------------------------
// Weight split+transpose: W[K][N] fp32 -> NS planes Wt[p][N][K].
// DUAL: blockIdx.z selects (W0->Wt0) vs (W1->Wt1).
// ---------------------------------------------------------------------------
template<int NS, bool DUAL>
__global__ __launch_bounds__(256) void wsplit_k(const float* __restrict__ W0,
                                                unsigned short* __restrict__ Wt0,
                                                const float* __restrict__ W1,
                                                unsigned short* __restrict__ Wt1,
                                                size_t plane)
{
    const float* W = W0;
    unsigned short* Wt = Wt0;
    if constexpr (DUAL) { if (blockIdx.z) { W = W1; Wt = Wt1; } }
    __shared__ float tile[64][65];
    const int t  = threadIdx.x;
    const int n0 = blockIdx.x * 64;
    const int k0 = blockIdx.y * 64;
    const int col = t & 63;
    const int rq  = t >> 6;

    #pragma unroll
    for (int p = 0; p < 16; ++p) {
        const int row = p * 4 + rq;                      // k-local
        tile[row][col] = W[(size_t)(k0 + row) * DMODEL + n0 + col];
    }
    __syncthreads();
    #pragma unroll
    for (int p = 0; p < 16; ++p) {
        const int nrow = p * 4 + rq;                     // n-local
        const float v = tile[col][nrow];                 // = W[k0+col][n0+nrow]
        const size_t o = (size_t)(n0 + nrow) * DMODEL + k0 + col;
        if (NS == 1) {
            Wt[o] = f2bf(v);
        } else {
            unsigned short u0, u1;
            split2(v, u0, u1);
            Wt[o] = u0; Wt[plane + o] = u1;
        }
    }
}

// ---------------------------------------------------------------------------
// MFMA GEMM on pre-split planes: C = A @ W^T + bias.
// 256-thread blocks (4 waves), BM=128 BN=64 BK=32; each wave a 64x32 sub-tile
// (4x2 frags of 16x16). LDS S[2][NS][192][32] = 48KB (NS=2) / 24KB (NS=1).
// T4 counted-vmcnt pipeline (vmcnt(6)/vmcnt(3), 0 only on last K-step);
// sched_barrier(0) pins (rule #18); T5 setprio around MFMA cluster.
// DUAL (Q+K merged): blockIdx.z selects problem -> 1024 blocks, 3 blocks/CU.
//
// NS=2 (fp16 split-2) hierarchical f32 fold (R12 -- replaces both R9's
// per-step fp64 fold and R11's spilling fp64 NF=4):
//   zacc[f] = mfma(P0a, P0b, zacc[f])  -- inner chain, 4 K-steps (128 prods)
//   every 4 steps: macc[f] += zacc[f]; zacc[f]=0  -- OUTER accumulator in
//   f32 (8 adds of ~0.35-magnitude partials -> ~1.7e-7 added error).
//   Total main-term error ~4e-7, below the scheme's dominant split-2 error
//   (~3e-7 rep + dropped P1P1); no fp64 array -> live regs 96 (facc+zacc+
//   macc), under the 3-waves/EU cap of 170 -> NO SPILL (R11's failure:
//   WRITE_SIZE 37->100MB scratch traffic from fp64 dacc spill).
// facc += P0a*P1b' + P1a'*P0b (2048-scaled, descaled 2^-11 at epilogue).
// ---------------------------------------------------------------------------
template<int NS, bool FOLD, bool SPLITOUT, bool DUAL>
__global__ __launch_bounds__(256, (NS == 1 ? 4 : 3))
void gemm_planes(const unsigned short* Ab0, const unsigned short* Bb0,
                 const float* bias0, float* __restrict__ Cp,
                 unsigned short* Pout0, float oscale0,
                 const unsigned short* Ab1, const unsigned short* Bb1,
                 const float* bias1, unsigned short* Pout1, float oscale1,
                 int M, int N, int K,
                 size_t planeA, size_t planeB, size_t planeO)
{
    const unsigned short* Ab = Ab0;
    const unsigned short* Bb = Bb0;
    const float* biasp = bias0;
    unsigned short* Pout = Pout0;
    float oscale = oscale0;
    if constexpr (DUAL) {
        if (blockIdx.z) { Ab = Ab1; Bb = Bb1; biasp = bias1; Pout = Pout1; oscale = oscale1; }
    }

    // rows 0..127 = A-tile, rows 128..191 = B-tile
    __shared__ unsigned short S[2][NS][192][32];

    const int t = threadIdx.x;
    const int w = t >> 6, l = t & 63, g = l >> 4, j = l & 15;
    const int wm = w >> 1;          // 0..1  (M direction, 64 rows each)
    const int wn = w & 1;           // 0..1  (N direction, 32 cols each)
    const int m0 = blockIdx.y * 128;
    const int n0 = blockIdx.x * 64;

    f32x4 facc[8];
    f32x4 zacc[8];
    f32x4 macc[8];
    #pragma unroll
    for (int f = 0; f < 8; ++f) {
        facc[f] = (f32x4){0.f, 0.f, 0.f, 0.f};
        zacc[f] = (f32x4){0.f, 0.f, 0.f, 0.f};
        macc[f] = (f32x4){0.f, 0.f, 0.f, 0.f};
    }

    // staging geometry: wave w stages rows [w*16, w*16+16) of each 64-row
    // chunk; lane -> row l>>2, source col-granule (l&3) ^ ((l>>3)&3)
    // (pre-swizzled global source; LDS dest linear per gload_lds rule).
    const int stgrow = w * 16 + (l >> 2);
    const int stgcol = ((l & 3) ^ ((l >> 3) & 3)) * 8;
    const unsigned short* gA = Ab + (size_t)(m0 + stgrow) * K + stgcol;
    const unsigned short* gB = Bb + (size_t)(n0 + stgrow) * K + stgcol;

    auto stage = [&](int buf, int k0) {
        #pragma unroll
        for (int p = 0; p < NS; ++p) {
            gload16(gA + (size_t)p * planeA + k0,                  &S[buf][p][w * 16][0]);
            gload16(gA + (size_t)p * planeA + (size_t)64 * K + k0, &S[buf][p][64 + w * 16][0]);
            gload16(gB + (size_t)p * planeB + k0,                  &S[buf][p][128 + w * 16][0]);
        }
    };

    // swizzled fragment column (elements): matches the staging swizzle
    const int gs8 = (g ^ ((j >> 1) & 3)) * 8;

    stage(0, 0);
    const int NT = K / 32;
    for (int kt = 0; kt < NT; ++kt) {
        const int cur = kt & 1;
        if (kt + 1 < NT) {
            stage(cur ^ 1, (kt + 1) * 32);   // issue next tile: stays in flight
            if constexpr (NS == 2) asm volatile("s_waitcnt vmcnt(6)" ::: "memory");
            else                   asm volatile("s_waitcnt vmcnt(3)" ::: "memory");
        } else {
            asm volatile("s_waitcnt vmcnt(0)" ::: "memory");
        }
        __builtin_amdgcn_sched_barrier(0);
        __builtin_amdgcn_s_barrier();        // buf[cur] ready on all waves
        __builtin_amdgcn_sched_barrier(0);

        if constexpr (NS == 1) {
            s16x8 a[4];
            #pragma unroll
            for (int mi = 0; mi < 4; ++mi)
                a[mi] = *(const s16x8*)&S[cur][0][wm * 64 + mi * 16 + j][gs8];
            __builtin_amdgcn_s_setprio(1);
            #pragma unroll
            for (int ni = 0; ni < 2; ++ni) {
                const int nr = 128 + wn * 32 + ni * 16 + j;
                s16x8 b0 = *(const s16x8*)&S[cur][0][nr][gs8];
                #pragma unroll
                for (int mi = 0; mi < 4; ++mi) {
                    const int f = mi * 2 + ni;
                    facc[f] = __builtin_amdgcn_mfma_f32_16x16x32_bf16(a[mi], b0, facc[f], 0, 0, 0);
                }
            }
            __builtin_amdgcn_s_setprio(0);
        } else {
            f16x8 a0[4], a1[4];
            #pragma unroll
            for (int mi = 0; mi < 4; ++mi) {
                a0[mi] = *(const f16x8*)&S[cur][0][wm * 64 + mi * 16 + j][gs8];
                a1[mi] = *(const f16x8*)&S[cur][1][wm * 64 + mi * 16 + j][gs8];
            }
            __builtin_amdgcn_s_setprio(1);
            #pragma unroll
            for (int ni = 0; ni < 2; ++ni) {
                const int nr = 128 + wn * 32 + ni * 16 + j;
                f16x8 b0 = *(const f16x8*)&S[cur][0][nr][gs8];
                f16x8 b1 = *(const f16x8*)&S[cur][1][nr][gs8];
                #pragma unroll
                for (int mi = 0; mi < 4; ++mi) {
                    const int f = mi * 2 + ni;
                    zacc[f] = __builtin_amdgcn_mfma_f32_16x16x32_f16(a0[mi], b0, zacc[f], 0, 0, 0);
                    facc[f] = __builtin_amdgcn_mfma_f32_16x16x32_f16(a0[mi], b1, facc[f], 0, 0, 0);
                    facc[f] = __builtin_amdgcn_mfma_f32_16x16x32_f16(a1[mi], b0, facc[f], 0, 0, 0);
                }
            }
            __builtin_amdgcn_s_setprio(0);
            // hierarchical fold: f32 outer accumulate every 4 K-steps
            if ((kt & 3) == 3 || kt == NT - 1) {
                #pragma unroll
                for (int f = 0; f < 8; ++f) {
                    macc[f] += zacc[f];
                    zacc[f] = (f32x4){0.f, 0.f, 0.f, 0.f};
                }
            }
        }

        __builtin_amdgcn_sched_barrier(0);
        __builtin_amdgcn_s_barrier();        // all reads of buf[cur] done
        __builtin_amdgcn_sched_barrier(0);
    }

    #pragma unroll
    for (int ni = 0; ni < 2; ++ni) {
        const int col = n0 + wn * 32 + ni * 16 + j;
        const float bv = biasp[col];
        #pragma unroll
        for (int mi = 0; mi < 4; ++mi) {
            const int f = mi * 2 + ni;
            #pragma unroll
            for (int r = 0; r < 4; ++r) {
                const int row = m0 + wm * 64 + mi * 16 + 4 * g + r;
                float val;
                if (FOLD) val = (float)((double)macc[f][r] + (double)facc[f][r] * (1.0 / 2048.0) + (double)bv);
                else      val = facc[f][r] + bv;
                if (SPLITOUT) {
                    const int bq = row >> 10, s = row & 1023;
                    const int h  = col >> 6,  d = col & 63;
                    const size_t o = (((size_t)(bq * 16 + h)) * SEQ + s) * HDIM + d;
                    unsigned short u0, u1;
                    split2(val * oscale, u0, u1);
                    Pout[o] = u0; Pout[planeO + o] = u1;
                } else {
                    Cp[(size_t)row * N + col] = val;
                }
            }
        }
    }
}

// ---------------------------------------------------------------------------
// Fused attention, single-pass: 128 q-rows/block (8 waves, one 16-row q-tile
// per wave), K chunks staged in LDS and shared by all 8 waves.
// q3/k3 are fp16 split-2 planes:
//   score = accM + (accC0+accC1) * 2^-11   (6 MFMAs/kb)
// T14 async-STAGE split: chunk ch+1's global loads issued right after the
// stage barrier of ch, consumed at the next iteration's ds_write.
// Online (m,Z) + dead-exp wave-uniform skip; exact fp64-cut prune; sparse PV
// gather (4-wide load batching). LDS ~52 KB -> 2 blocks/CU; grid 512 = 2/CU.
// UNCHANGED from round 9.
// ---------------------------------------------------------------------------
#define CAND 32
#define QROWS 128
__global__ __launch_bounds__(512, 4) void attn_k(const unsigned short* __restrict__ q3,
                                                 const unsigned short* __restrict__ k3,
                                                 const float* __restrict__ vf,
                                                 unsigned short* __restrict__ attnb,
                                                 size_t plane)
{
    __shared__ unsigned short Ks[2][64][72];   // 18.4 KB
    __shared__ int   ckey[QROWS][CAND];        // 16 KB
    __shared__ float csc[QROWS][CAND];         // 16 KB
    __shared__ int   ccnt[QROWS];
    __shared__ float zinv[QROWS];

    const int t  = threadIdx.x;
    const int w  = t >> 6, l = t & 63, g = l >> 4, j = l & 15;
    const int bh = blockIdx.x >> 3;     // 0..63
    const int qt = blockIdx.x & 7;      // 0..7 (128-row q groups)
    const int b  = bh >> 4, h = bh & 15;

    if (t < QROWS) ccnt[t] = 0;

    // A-frags for this wave's 16 q-rows (q pre-scaled 1/8 in planes)
    f16x8 aq[2][2];
    {
        const size_t qoff = ((size_t)bh * SEQ + qt * QROWS + w * 16 + j) * HDIM + g * 8;
        #pragma unroll
        for (int p = 0; p < 2; ++p)
            #pragma unroll
            for (int half = 0; half < 2; ++half)
                aq[p][half] = *(const f16x8*)(q3 + p * plane + qoff + half * 32);
    }

    // staging: 512 threads, each one uint4 (8 elems) per plane
    const int skey = t >> 3;            // staging key-local 0..63
    const int soff = (t & 7) * 8;       // element offset 0..56
    const unsigned short* ksrc = k3 + (size_t)bh * (SEQ * HDIM) + (size_t)skey * HDIM + soff;

    float rm[4], rz[4];
    #pragma unroll
    for (int r = 0; r < 4; ++r) { rm[r] = -INFINITY; rz[r] = 0.f; }

    // T14 prologue: chunk 0 loads in flight before the loop
    uint4 stg0 = *(const uint4*)(ksrc);
    uint4 stg1 = *(const uint4*)(ksrc + plane);

    for (int ch = 0; ch < 16; ++ch) {
        __syncthreads();                      // Ks free (prev readers done)
        *(uint4*)&Ks[0][skey][soff] = stg0;
        *(uint4*)&Ks[1][skey][soff] = stg1;
        __syncthreads();                      // Ks ready
        // issue next chunk's loads now; consumed at next iteration's ds_write
        if (ch + 1 < 16) {
            const unsigned short* s = ksrc + (ch + 1) * 4096;
            stg0 = *(const uint4*)(s);
            stg1 = *(const uint4*)(s + plane);
        }

        float sc[4][4];   // [kb][r]
        __builtin_amdgcn_s_setprio(1);
        #pragma unroll
        for (int kb = 0; kb < 4; ++kb) {
            f32x4 accM = {0.f,0.f,0.f,0.f};
            f32x4 accC0 = {0.f,0.f,0.f,0.f}, accC1 = {0.f,0.f,0.f,0.f};
            const int kr = kb * 16 + j;
            #pragma unroll
            for (int half = 0; half < 2; ++half) {
                f16x8 b0 = *(const f16x8*)&Ks[0][kr][half * 32 + g * 8];
                f16x8 b1 = *(const f16x8*)&Ks[1][kr][half * 32 + g * 8];
                accM  = __builtin_amdgcn_mfma_f32_16x16x32_f16(aq[0][half], b0, accM,  0, 0, 0);
                accC0 = __builtin_amdgcn_mfma_f32_16x16x32_f16(aq[0][half], b1, accC0, 0, 0, 0);
                accC1 = __builtin_amdgcn_mfma_f32_16x16x32_f16(aq[1][half], b0, accC1, 0, 0, 0);
            }
            #pragma unroll
            for (int r = 0; r < 4; ++r)
                sc[kb][r] = accM[r] + (accC0[r] + accC1[r]) * (1.0f / 2048.0f);
        }
        __builtin_amdgcn_s_setprio(0);

        // online (m,Z) with row-global running max + candidate capture
        #pragma unroll
        for (int r = 0; r < 4; ++r) {
            float nmc = fmaxf(fmaxf(sc[0][r], sc[1][r]), fmaxf(sc[2][r], sc[3][r]));
            #pragma unroll
            for (int off = 1; off < 16; off <<= 1) nmc = fmaxf(nmc, __shfl_xor(nmc, off));
            // dead-exp skip: all terms sub-half-ulp of rz and no candidate can
            // pass thr=rm-0.004 -> wave-uniform skip (no barrier inside).
            if (__all(nmc <= rm[r] - 0.03f)) continue;
            const float nm = fmaxf(nmc, rm[r]);
            float add = 0.f;
            #pragma unroll
            for (int kb = 0; kb < 4; ++kb) add += __expf((sc[kb][r] - nm) * 1000.f);
            rz[r] = rz[r] * __expf((rm[r] - nm) * 1000.f) + add;
            rm[r] = nm;
            const float thr = nm - 0.004f;   // cut >= m_final-0.00396 >= nm-0.00396
            #pragma unroll
            for (int kb = 0; kb < 4; ++kb) {
                if (sc[kb][r] >= thr) {
                    const int row = w * 16 + 4 * g + r;
                    const int pos = atomicAdd(&ccnt[row], 1);
                    if (pos < CAND) {
                        ckey[row][pos] = ch * 64 + kb * 16 + j;
                        csc[row][pos]  = sc[kb][r];
                    }
                }
            }
        }
    }
    __syncthreads();

    // finalize: Z reduce across 16 lanes, exact cut, prune+compact candidates
    float Zr[4];
    #pragma unroll
    for (int r = 0; r < 4; ++r) {
        float z = rz[r];
        #pragma unroll
        for (int off = 1; off < 16; off <<= 1) z += __shfl_xor(z, off);
        Zr[r] = z;
    }
    #pragma unroll
    for (int r = 0; r < 4; ++r) {
        if (j == r) {
            const int row = w * 16 + 4 * g + r;
            const double cut = (double)rm[r] + 0.001 * log(0.019 * (double)Zr[r]);
            const int craw = ccnt[row];
            const int c = craw < CAND ? craw : CAND;
            int n = 0; float z2 = 0.f;
            for (int i = 0; i < c; ++i) {
                const float s = csc[row][i];
                if ((double)s >= cut) {
                    const float ev = __expf(s - rm[r]);
                    ckey[row][n] = ckey[row][i];
                    csc[row][n]  = ev;
                    z2 += ev; ++n;
                }
            }
            ccnt[row] = (craw > CAND) ? -1 : n;   // -1 = overflow sentinel
            zinv[row] = (n > 0) ? 1.f / z2 : 0.f;
        }
    }
    __syncthreads();

    // sparse PV gather (wave w handles its own 16 rows; lane l = dim).
    // 4-way load batching; fmac order matches the serial loop.
    const float* vbase = vf + (size_t)b * SEQ * DMODEL + h * HDIM + l;
    for (int i = 0; i < 16; ++i) {
        const int row = w * 16 + i;
        const int n = ccnt[row];
        float o = 0.f;
        if (n == 0) {
            // all masked -> uniform weights over all 1024 keys
            for (int kk = 0; kk < SEQ; ++kk) o += vbase[(size_t)kk * DMODEL];
            o *= (1.0f / 1024.0f);
        } else if (n < 0) {
            o = INFINITY;   // candidate overflow sentinel (P ~ 1e-6)
        } else {
            const float inv = zinv[row];
            int i2 = 0;
            for (; i2 + 4 <= n; i2 += 4) {
                const float c0 = csc[row][i2 + 0], c1 = csc[row][i2 + 1];
                const float c2 = csc[row][i2 + 2], c3 = csc[row][i2 + 3];
                const float v0 = vbase[(size_t)ckey[row][i2 + 0] * DMODEL];
                const float v1 = vbase[(size_t)ckey[row][i2 + 1] * DMODEL];
                const float v2 = vbase[(size_t)ckey[row][i2 + 2] * DMODEL];
                const float v3 = vbase[(size_t)ckey[row][i2 + 3] * DMODEL];
                o += c0 * v0; o += c1 * v1; o += c2 * v2; o += c3 * v3;
            }
            for (; i2 < n; ++i2)
                o += csc[row][i2] * vbase[(size_t)ckey[row][i2] * DMODEL];
            o *= inv;
        }
        attnb[((size_t)b * SEQ + qt * QROWS + row) * DMODEL + h * HDIM + l] = f2bf(o);
    }
}

// ---------------------------------------------------------------------------
extern "C" void kernel_launch(void* const* d_in, const int* in_sizes, int n_in,
                              void* d_out, int out_size, void* d_ws, size_t ws_size,
                              hipStream_t stream) {
    const float* Q  = (const float*)d_in[0];
    const float* K  = (const float*)d_in[1];
    const float* V  = (const float*)d_in[2];
    const float* Wq = (const float*)d_in[3];
    const float* bq = (const float*)d_in[4];
    const float* Wk = (const float*)d_in[5];
    const float* bk = (const float*)d_in[6];
    const float* Wv = (const float*)d_in[7];
    const float* bv = (const float*)d_in[8];
    const float* Wo = (const float*)d_in[9];
    const float* bo = (const float*)d_in[10];

    const size_t PLANE  = (size_t)MROWS * DMODEL;     // 4 Mi elements
    const size_t WPLANE = (size_t)DMODEL * DMODEL;

    // Workspace layout (90 MiB total):
    unsigned short* R1 = (unsigned short*)d_ws;        // 2P: V split (1P) -> Q split -> attnb
    unsigned short* R2 = R1 + 2 * PLANE;               // 2P: K split
    unsigned short* W1 = R2 + 2 * PLANE;               // 1W: Wv, later Wo
    unsigned short* W2 = W1 + WPLANE;                  // 2W: Wq planes
    unsigned short* W3 = W2 + 2 * WPLANE;              // 2W: Wk planes
    unsigned short* q3 = W3 + 2 * WPLANE;              // 2P
    unsigned short* k3 = q3 + 2 * PLANE;               // 2P
    float*          vf = (float*)(k3 + 2 * PLANE);     // PLANE f32
    unsigned short* attnb = R1;                        // reuse after QK GEMM

    dim3 blk(256, 1, 1);
    const int nvec = (int)(PLANE / 8);
    dim3 gs((nvec + 255) / 256, 1, 1);
    dim3 gs2((nvec + 255) / 256, 2, 1);
    dim3 gw(DMODEL / 64, DMODEL / 64, 1);
    dim3 gw2(DMODEL / 64, DMODEL / 64, 2);
    dim3 gg(DMODEL / 64, MROWS / 128, 1);              // 512 blocks (NS=1)
    dim3 gg2(DMODEL / 64, MROWS / 128, 2);             // 1024 blocks (merged Q+K)

    // ---- V projection first (frees R1 for Q split) ----
    splitx_k<1, false><<<gs, blk, 0, stream>>>(V, R1, nullptr, nullptr, nvec, PLANE);
    wsplit_k<1, false><<<gw, blk, 0, stream>>>(Wv, W1, nullptr, nullptr, WPLANE);
    gemm_planes<1, false, false, false><<<gg, blk, 0, stream>>>(
        R1, W1, bv, vf, nullptr, 1.0f,
        nullptr, nullptr, nullptr, nullptr, 0.f,
        MROWS, DMODEL, DMODEL, PLANE, WPLANE, PLANE);

    // ---- Q+K splits and projections, merged dispatches ----
    splitx_k<2, true><<<gs2, blk, 0, stream>>>(Q, R1, K, R2, nvec, PLANE);
    wsplit_k<2, true><<<gw2, blk, 0, stream>>>(Wq, W2, Wk, W3, WPLANE);
    gemm_planes<2, true, true, true><<<gg2, blk, 0, stream>>>(
        R1, W2, bq, nullptr, q3, 0.125f,
        R2, W3, bk, k3, 1.0f,
        MROWS, DMODEL, DMODEL, PLANE, WPLANE, PLANE);

    // ---- fused masked attention (single pass) -> bf16 attnb ----
    attn_k<<<dim3(64 * 8, 1, 1), dim3(512, 1, 1), 0, stream>>>(q3, k3, vf, attnb, PLANE);

    // ---- O projection (plain bf16 MFMA) -> fp32 d_out ----
    wsplit_k<1, false><<<gw, blk, 0, stream>>>(Wo, W1, nullptr, nullptr, WPLANE);
    gemm_planes<1, false, false, false><<<gg, blk, 0, stream>>>(
        attnb, W1, bo, (float*)d_out, nullptr, 1.0f,
        nullptr, nullptr, nullptr, nullptr, 0.f,
        MROWS, DMODEL, DMODEL, PLANE, WPLANE, PLANE);
}

// Round 13
// 288.223 us; speedup vs baseline: 1.3208x; 1.0144x over previous
//
#include <hip/hip_runtime.h>
#include <hip/hip_bf16.h>
#include <math.h>

// Problem constants (B=4, S=1024, D=1024, H=16, hd=64)
#define SEQ    1024
#define DMODEL 1024
#define NHEAD  16
#define HDIM   64
#define BATCH  4
#define MROWS  4096   // B*S

typedef float f32x4 __attribute__((ext_vector_type(4)));
typedef short s16x8 __attribute__((ext_vector_type(8)));
typedef _Float16 f16x8 __attribute__((ext_vector_type(8)));

__device__ __forceinline__ float bf2f(unsigned short u) {
    return __uint_as_float(((unsigned int)u) << 16);
}
__device__ __forceinline__ unsigned short f2bf(float f) {
    __hip_bfloat16 h = __float2bfloat16(f);   // RNE
    return *reinterpret_cast<unsigned short*>(&h);
}
// fp16 helpers (RNE)
__device__ __forceinline__ unsigned short f2h(float f) {
    _Float16 h = (_Float16)f;
    return *reinterpret_cast<unsigned short*>(&h);
}
__device__ __forceinline__ float h2f(unsigned short u) {
    _Float16 h = *reinterpret_cast<_Float16*>(&u);
    return (float)h;
}
// scaled fp16 split-2: x ~= h0 + h1 * 2^-11,  h1 stored PRE-SCALED by 2048
// so residuals stay in fp16 normal range. Representation error ~1.2e-7 |x|.
__device__ __forceinline__ void split2(float x, unsigned short& u0, unsigned short& u1) {
    u0 = f2h(x);
    float f0 = h2f(u0);
    u1 = f2h((x - f0) * 2048.0f);
}

// async global->LDS, 16B per lane, dest = wave-uniform base + lane*16
__device__ __forceinline__ void gload16(const void* g, void* l) {
    __builtin_amdgcn_global_load_lds(
        (const __attribute__((address_space(1))) unsigned int*)g,
        (__attribute__((address_space(3))) unsigned int*)l, 16, 0, 0);
}

// ---------------------------------------------------------------------------
// Input split: X[n] fp32 -> planes.
//   NS=1: single bf16 plane.   NS=2: fp16 split-2 planes (h1 pre-scaled 2048).
// DUAL: blockIdx.y selects (X0->P0) vs (X1->P1) -- Q and K in one dispatch.
// ---------------------------------------------------------------------------
template<int NS, bool DUAL>
__global__ __launch_bounds__(256) void splitx_k(const float* __restrict__ X0,
                                                unsigned short* __restrict__ P0,
                                                const float* __restrict__ X1,
                                                unsigned short* __restrict__ P1,
                                                int nvec, size_t plane)
{
    const float* X = X0;
    unsigned short* P = P0;
    if constexpr (DUAL) { if (blockIdx.y) { X = X1; P = P1; } }
    const int i = blockIdx.x * 256 + threadIdx.x;   // 8-element vector index
    if (i >= nvec) return;
    const float* src = X + (size_t)i * 8;
    float4 v0 = *(const float4*)src;
    float4 v1 = *(const float4*)(src + 4);
    float x[8] = {v0.x, v0.y, v0.z, v0.w, v1.x, v1.y, v1.z, v1.w};
    unsigned short p0[8], p1[8];
    #pragma unroll
    for (int e = 0; e < 8; ++e) {
        if (NS == 1) { p0[e] = f2bf(x[e]); }
        else         { split2(x[e], p0[e], p1[e]); }
    }
    *(uint4*)(P + (size_t)i * 8) = *(uint4*)p0;
    if (NS == 2) {
        *(uint4*)(P + plane + (size_t)i * 8) = *(uint4*)p1;
    }
}

// ---------------------------------------------------------------------------
// Weight split+transpose: W[K][N] fp32 -> NS planes Wt[p][N][K].
// DUAL: blockIdx.z selects (W0->Wt0) vs (W1->Wt1).
// ---------------------------------------------------------------------------
template<int NS, bool DUAL>
__global__ __launch_bounds__(256) void wsplit_k(const float* __restrict__ W0,
                                                unsigned short* __restrict__ Wt0,
                                                const float* __restrict__ W1,
                                                unsigned short* __restrict__ Wt1,
                                                size_t plane)
{
    const float* W = W0;
    unsigned short* Wt = Wt0;
    if constexpr (DUAL) { if (blockIdx.z) { W = W1; Wt = Wt1; } }
    __shared__ float tile[64][65];
    const int t  = threadIdx.x;
    const int n0 = blockIdx.x * 64;
    const int k0 = blockIdx.y * 64;
    const int col = t & 63;
    const int rq  = t >> 6;

    #pragma unroll
    for (int p = 0; p < 16; ++p) {
        const int row = p * 4 + rq;                      // k-local
        tile[row][col] = W[(size_t)(k0 + row) * DMODEL + n0 + col];
    }
    __syncthreads();
    #pragma unroll
    for (int p = 0; p < 16; ++p) {
        const int nrow = p * 4 + rq;                     // n-local
        const float v = tile[col][nrow];                 // = W[k0+col][n0+nrow]
        const size_t o = (size_t)(n0 + nrow) * DMODEL + k0 + col;
        if (NS == 1) {
            Wt[o] = f2bf(v);
        } else {
            unsigned short u0, u1;
            split2(v, u0, u1);
            Wt[o] = u0; Wt[plane + o] = u1;
        }
    }
}

// ---------------------------------------------------------------------------
// MFMA GEMM on pre-split planes: C = A @ W^T + bias.
// 256-thread blocks (4 waves), BM=128 BN=64 BK=32; each wave a 64x32 sub-tile
// (4x2 frags of 16x16). LDS S[2][NS][192][32] = 48KB (NS=2) / 24KB (NS=1).
// T4 counted-vmcnt pipeline (vmcnt(6)/vmcnt(3), 0 only on last K-step);
// sched_barrier(0) pins (rule #18); T5 setprio around MFMA cluster.
// DUAL (Q+K merged): blockIdx.z selects problem -> 1024 blocks, 3 blocks/CU.
//
// R13: T1 chunked XCD swizzle. Default dispatch round-robins consecutive
// blocks across the 8 XCDs, and x (n-tile) is fastest -> the 16 blocks
// sharing one 512KB A-panel land on 8 different L2s (FETCH 147MB vs ~40MB
// compulsory). Remap the flattened x-y id with swz=(bid&7)*64+(bid>>3)
// (bijective, nwg=512 % 8 == 0; z-slices preserve bid%8) so each XCD owns
// 4 contiguous m-panels -> each A-panel is fetched into exactly one L2.
// Pure work remap: outputs BIT-IDENTICAL.
//
// NS=2 (fp16 split-2) hierarchical f32 fold:
//   zacc[f] = mfma(P0a, P0b, zacc[f])  -- inner chain, 4 K-steps
//   every 4 steps: macc[f] += zacc[f]; zacc[f]=0  (f32 outer, no fp64 array
//   -> 96 live regs, no spill).  facc += P0a*P1b' + P1a'*P0b (2048-scaled,
//   descaled 2^-11 at epilogue).
// ---------------------------------------------------------------------------
template<int NS, bool FOLD, bool SPLITOUT, bool DUAL>
__global__ __launch_bounds__(256, (NS == 1 ? 4 : 3))
void gemm_planes(const unsigned short* Ab0, const unsigned short* Bb0,
                 const float* bias0, float* __restrict__ Cp,
                 unsigned short* Pout0, float oscale0,
                 const unsigned short* Ab1, const unsigned short* Bb1,
                 const float* bias1, unsigned short* Pout1, float oscale1,
                 int M, int N, int K,
                 size_t planeA, size_t planeB, size_t planeO)
{
    const unsigned short* Ab = Ab0;
    const unsigned short* Bb = Bb0;
    const float* biasp = bias0;
    unsigned short* Pout = Pout0;
    float oscale = oscale0;
    if constexpr (DUAL) {
        if (blockIdx.z) { Ab = Ab1; Bb = Bb1; biasp = bias1; Pout = Pout1; oscale = oscale1; }
    }

    // T1 chunked XCD swizzle (bijective since nwg = 16*32 = 512, 512%8==0)
    const int nbx = gridDim.x;
    const int nwg = nbx * gridDim.y;          // 512
    int bid = blockIdx.y * nbx + blockIdx.x;
    bid = (bid & 7) * (nwg >> 3) + (bid >> 3);
    const int m0 = (bid / nbx) * 128;
    const int n0 = (bid % nbx) * 64;

    // rows 0..127 = A-tile, rows 128..191 = B-tile
    __shared__ unsigned short S[2][NS][192][32];

    const int t = threadIdx.x;
    const int w = t >> 6, l = t & 63, g = l >> 4, j = l & 15;
    const int wm = w >> 1;          // 0..1  (M direction, 64 rows each)
    const int wn = w & 1;           // 0..1  (N direction, 32 cols each)

    f32x4 facc[8];
    f32x4 zacc[8];
    f32x4 macc[8];
    #pragma unroll
    for (int f = 0; f < 8; ++f) {
        facc[f] = (f32x4){0.f, 0.f, 0.f, 0.f};
        zacc[f] = (f32x4){0.f, 0.f, 0.f, 0.f};
        macc[f] = (f32x4){0.f, 0.f, 0.f, 0.f};
    }

    // staging geometry: wave w stages rows [w*16, w*16+16) of each 64-row
    // chunk; lane -> row l>>2, source col-granule (l&3) ^ ((l>>3)&3)
    // (pre-swizzled global source; LDS dest linear per gload_lds rule).
    const int stgrow = w * 16 + (l >> 2);
    const int stgcol = ((l & 3) ^ ((l >> 3) & 3)) * 8;
    const unsigned short* gA = Ab + (size_t)(m0 + stgrow) * K + stgcol;
    const unsigned short* gB = Bb + (size_t)(n0 + stgrow) * K + stgcol;

    auto stage = [&](int buf, int k0) {
        #pragma unroll
        for (int p = 0; p < NS; ++p) {
            gload16(gA + (size_t)p * planeA + k0,                  &S[buf][p][w * 16][0]);
            gload16(gA + (size_t)p * planeA + (size_t)64 * K + k0, &S[buf][p][64 + w * 16][0]);
            gload16(gB + (size_t)p * planeB + k0,                  &S[buf][p][128 + w * 16][0]);
        }
    };

    // swizzled fragment column (elements): matches the staging swizzle
    const int gs8 = (g ^ ((j >> 1) & 3)) * 8;

    stage(0, 0);
    const int NT = K / 32;
    for (int kt = 0; kt < NT; ++kt) {
        const int cur = kt & 1;
        if (kt + 1 < NT) {
            stage(cur ^ 1, (kt + 1) * 32);   // issue next tile: stays in flight
            if constexpr (NS == 2) asm volatile("s_waitcnt vmcnt(6)" ::: "memory");
            else                   asm volatile("s_waitcnt vmcnt(3)" ::: "memory");
        } else {
            asm volatile("s_waitcnt vmcnt(0)" ::: "memory");
        }
        __builtin_amdgcn_sched_barrier(0);
        __builtin_amdgcn_s_barrier();        // buf[cur] ready on all waves
        __builtin_amdgcn_sched_barrier(0);

        if constexpr (NS == 1) {
            s16x8 a[4];
            #pragma unroll
            for (int mi = 0; mi < 4; ++mi)
                a[mi] = *(const s16x8*)&S[cur][0][wm * 64 + mi * 16 + j][gs8];
            __builtin_amdgcn_s_setprio(1);
            #pragma unroll
            for (int ni = 0; ni < 2; ++ni) {
                const int nr = 128 + wn * 32 + ni * 16 + j;
                s16x8 b0 = *(const s16x8*)&S[cur][0][nr][gs8];
                #pragma unroll
                for (int mi = 0; mi < 4; ++mi) {
                    const int f = mi * 2 + ni;
                    facc[f] = __builtin_amdgcn_mfma_f32_16x16x32_bf16(a[mi], b0, facc[f], 0, 0, 0);
                }
            }
            __builtin_amdgcn_s_setprio(0);
        } else {
            f16x8 a0[4], a1[4];
            #pragma unroll
            for (int mi = 0; mi < 4; ++mi) {
                a0[mi] = *(const f16x8*)&S[cur][0][wm * 64 + mi * 16 + j][gs8];
                a1[mi] = *(const f16x8*)&S[cur][1][wm * 64 + mi * 16 + j][gs8];
            }
            __builtin_amdgcn_s_setprio(1);
            #pragma unroll
            for (int ni = 0; ni < 2; ++ni) {
                const int nr = 128 + wn * 32 + ni * 16 + j;
                f16x8 b0 = *(const f16x8*)&S[cur][0][nr][gs8];
                f16x8 b1 = *(const f16x8*)&S[cur][1][nr][gs8];
                #pragma unroll
                for (int mi = 0; mi < 4; ++mi) {
                    const int f = mi * 2 + ni;
                    zacc[f] = __builtin_amdgcn_mfma_f32_16x16x32_f16(a0[mi], b0, zacc[f], 0, 0, 0);
                    facc[f] = __builtin_amdgcn_mfma_f32_16x16x32_f16(a0[mi], b1, facc[f], 0, 0, 0);
                    facc[f] = __builtin_amdgcn_mfma_f32_16x16x32_f16(a1[mi], b0, facc[f], 0, 0, 0);
                }
            }
            __builtin_amdgcn_s_setprio(0);
            // hierarchical fold: f32 outer accumulate every 4 K-steps
            if ((kt & 3) == 3 || kt == NT - 1) {
                #pragma unroll
                for (int f = 0; f < 8; ++f) {
                    macc[f] += zacc[f];
                    zacc[f] = (f32x4){0.f, 0.f, 0.f, 0.f};
                }
            }
        }

        __builtin_amdgcn_sched_barrier(0);
        __builtin_amdgcn_s_barrier();        // all reads of buf[cur] done
        __builtin_amdgcn_sched_barrier(0);
    }

    #pragma unroll
    for (int ni = 0; ni < 2; ++ni) {
        const int col = n0 + wn * 32 + ni * 16 + j;
        const float bv = biasp[col];
        #pragma unroll
        for (int mi = 0; mi < 4; ++mi) {
            const int f = mi * 2 + ni;
            #pragma unroll
            for (int r = 0; r < 4; ++r) {
                const int row = m0 + wm * 64 + mi * 16 + 4 * g + r;
                float val;
                if (FOLD) val = (float)((double)macc[f][r] + (double)facc[f][r] * (1.0 / 2048.0) + (double)bv);
                else      val = facc[f][r] + bv;
                if (SPLITOUT) {
                    const int bq = row >> 10, s = row & 1023;
                    const int h  = col >> 6,  d = col & 63;
                    const size_t o = (((size_t)(bq * 16 + h)) * SEQ + s) * HDIM + d;
                    unsigned short u0, u1;
                    split2(val * oscale, u0, u1);
                    Pout[o] = u0; Pout[planeO + o] = u1;
                } else {
                    Cp[(size_t)row * N + col] = val;
                }
            }
        }
    }
}

// ---------------------------------------------------------------------------
// Fused attention, single-pass: 128 q-rows/block (8 waves, one 16-row q-tile
// per wave), K chunks staged in LDS and shared by all 8 waves.
// q3/k3 are fp16 split-2 planes:
//   score = accM + (accC0+accC1) * 2^-11   (6 MFMAs/kb)
// T14 async-STAGE split: chunk ch+1's global loads issued right after the
// stage barrier of ch, consumed at the next iteration's ds_write.
// Online (m,Z) + dead-exp wave-uniform skip; exact fp64-cut prune; sparse PV
// gather (4-wide load batching). LDS ~52 KB -> 2 blocks/CU; grid 512 = 2/CU.
// UNCHANGED from round 9.
// ---------------------------------------------------------------------------
#define CAND 32
#define QROWS 128
__global__ __launch_bounds__(512, 4) void attn_k(const unsigned short* __restrict__ q3,
                                                 const unsigned short* __restrict__ k3,
                                                 const float* __restrict__ vf,
                                                 unsigned short* __restrict__ attnb,
                                                 size_t plane)
{
    __shared__ unsigned short Ks[2][64][72];   // 18.4 KB
    __shared__ int   ckey[QROWS][CAND];        // 16 KB
    __shared__ float csc[QROWS][CAND];         // 16 KB
    __shared__ int   ccnt[QROWS];
    __shared__ float zinv[QROWS];

    const int t  = threadIdx.x;
    const int w  = t >> 6, l = t & 63, g = l >> 4, j = l & 15;
    const int bh = blockIdx.x >> 3;     // 0..63
    const int qt = blockIdx.x & 7;      // 0..7 (128-row q groups)
    const int b  = bh >> 4, h = bh & 15;

    if (t < QROWS) ccnt[t] = 0;

    // A-frags for this wave's 16 q-rows (q pre-scaled 1/8 in planes)
    f16x8 aq[2][2];
    {
        const size_t qoff = ((size_t)bh * SEQ + qt * QROWS + w * 16 + j) * HDIM + g * 8;
        #pragma unroll
        for (int p = 0; p < 2; ++p)
            #pragma unroll
            for (int half = 0; half < 2; ++half)
                aq[p][half] = *(const f16x8*)(q3 + p * plane + qoff + half * 32);
    }

    // staging: 512 threads, each one uint4 (8 elems) per plane
    const int skey = t >> 3;            // staging key-local 0..63
    const int soff = (t & 7) * 8;       // element offset 0..56
    const unsigned short* ksrc = k3 + (size_t)bh * (SEQ * HDIM) + (size_t)skey * HDIM + soff;

    float rm[4], rz[4];
    #pragma unroll
    for (int r = 0; r < 4; ++r) { rm[r] = -INFINITY; rz[r] = 0.f; }

    // T14 prologue: chunk 0 loads in flight before the loop
    uint4 stg0 = *(const uint4*)(ksrc);
    uint4 stg1 = *(const uint4*)(ksrc + plane);

    for (int ch = 0; ch < 16; ++ch) {
        __syncthreads();                      // Ks free (prev readers done)
        *(uint4*)&Ks[0][skey][soff] = stg0;
        *(uint4*)&Ks[1][skey][soff] = stg1;
        __syncthreads();                      // Ks ready
        // issue next chunk's loads now; consumed at next iteration's ds_write
        if (ch + 1 < 16) {
            const unsigned short* s = ksrc + (ch + 1) * 4096;
            stg0 = *(const uint4*)(s);
            stg1 = *(const uint4*)(s + plane);
        }

        float sc[4][4];   // [kb][r]
        __builtin_amdgcn_s_setprio(1);
        #pragma unroll
        for (int kb = 0; kb < 4; ++kb) {
            f32x4 accM = {0.f,0.f,0.f,0.f};
            f32x4 accC0 = {0.f,0.f,0.f,0.f}, accC1 = {0.f,0.f,0.f,0.f};
            const int kr = kb * 16 + j;
            #pragma unroll
            for (int half = 0; half < 2; ++half) {
                f16x8 b0 = *(const f16x8*)&Ks[0][kr][half * 32 + g * 8];
                f16x8 b1 = *(const f16x8*)&Ks[1][kr][half * 32 + g * 8];
                accM  = __builtin_amdgcn_mfma_f32_16x16x32_f16(aq[0][half], b0, accM,  0, 0, 0);
                accC0 = __builtin_amdgcn_mfma_f32_16x16x32_f16(aq[0][half], b1, accC0, 0, 0, 0);
                accC1 = __builtin_amdgcn_mfma_f32_16x16x32_f16(aq[1][half], b0, accC1, 0, 0, 0);
            }
            #pragma unroll
            for (int r = 0; r < 4; ++r)
                sc[kb][r] = accM[r] + (accC0[r] + accC1[r]) * (1.0f / 2048.0f);
        }
        __builtin_amdgcn_s_setprio(0);

        // online (m,Z) with row-global running max + candidate capture
        #pragma unroll
        for (int r = 0; r < 4; ++r) {
            float nmc = fmaxf(fmaxf(sc[0][r], sc[1][r]), fmaxf(sc[2][r], sc[3][r]));
            #pragma unroll
            for (int off = 1; off < 16; off <<= 1) nmc = fmaxf(nmc, __shfl_xor(nmc, off));
            // dead-exp skip: all terms sub-half-ulp of rz and no candidate can
            // pass thr=rm-0.004 -> wave-uniform skip (no barrier inside).
            if (__all(nmc <= rm[r] - 0.03f)) continue;
            const float nm = fmaxf(nmc, rm[r]);
            float add = 0.f;
            #pragma unroll
            for (int kb = 0; kb < 4; ++kb) add += __expf((sc[kb][r] - nm) * 1000.f);
            rz[r] = rz[r] * __expf((rm[r] - nm) * 1000.f) + add;
            rm[r] = nm;
            const float thr = nm - 0.004f;   // cut >= m_final-0.00396 >= nm-0.00396
            #pragma unroll
            for (int kb = 0; kb < 4; ++kb) {
                if (sc[kb][r] >= thr) {
                    const int row = w * 16 + 4 * g + r;
                    const int pos = atomicAdd(&ccnt[row], 1);
                    if (pos < CAND) {
                        ckey[row][pos] = ch * 64 + kb * 16 + j;
                        csc[row][pos]  = sc[kb][r];
                    }
                }
            }
        }
    }
    __syncthreads();

    // finalize: Z reduce across 16 lanes, exact cut, prune+compact candidates
    float Zr[4];
    #pragma unroll
    for (int r = 0; r < 4; ++r) {
        float z = rz[r];
        #pragma unroll
        for (int off = 1; off < 16; off <<= 1) z += __shfl_xor(z, off);
        Zr[r] = z;
    }
    #pragma unroll
    for (int r = 0; r < 4; ++r) {
        if (j == r) {
            const int row = w * 16 + 4 * g + r;
            const double cut = (double)rm[r] + 0.001 * log(0.019 * (double)Zr[r]);
            const int craw = ccnt[row];
            const int c = craw < CAND ? craw : CAND;
            int n = 0; float z2 = 0.f;
            for (int i = 0; i < c; ++i) {
                const float s = csc[row][i];
                if ((double)s >= cut) {
                    const float ev = __expf(s - rm[r]);
                    ckey[row][n] = ckey[row][i];
                    csc[row][n]  = ev;
                    z2 += ev; ++n;
                }
            }
            ccnt[row] = (craw > CAND) ? -1 : n;   // -1 = overflow sentinel
            zinv[row] = (n > 0) ? 1.f / z2 : 0.f;
        }
    }
    __syncthreads();

    // sparse PV gather (wave w handles its own 16 rows; lane l = dim).
    // 4-way load batching; fmac order matches the serial loop.
    const float* vbase = vf + (size_t)b * SEQ * DMODEL + h * HDIM + l;
    for (int i = 0; i < 16; ++i) {
        const int row = w * 16 + i;
        const int n = ccnt[row];
        float o = 0.f;
        if (n == 0) {
            // all masked -> uniform weights over all 1024 keys
            for (int kk = 0; kk < SEQ; ++kk) o += vbase[(size_t)kk * DMODEL];
            o *= (1.0f / 1024.0f);
        } else if (n < 0) {
            o = INFINITY;   // candidate overflow sentinel (P ~ 1e-6)
        } else {
            const float inv = zinv[row];
            int i2 = 0;
            for (; i2 + 4 <= n; i2 += 4) {
                const float c0 = csc[row][i2 + 0], c1 = csc[row][i2 + 1];
                const float c2 = csc[row][i2 + 2], c3 = csc[row][i2 + 3];
                const float v0 = vbase[(size_t)ckey[row][i2 + 0] * DMODEL];
                const float v1 = vbase[(size_t)ckey[row][i2 + 1] * DMODEL];
                const float v2 = vbase[(size_t)ckey[row][i2 + 2] * DMODEL];
                const float v3 = vbase[(size_t)ckey[row][i2 + 3] * DMODEL];
                o += c0 * v0; o += c1 * v1; o += c2 * v2; o += c3 * v3;
            }
            for (; i2 < n; ++i2)
                o += csc[row][i2] * vbase[(size_t)ckey[row][i2] * DMODEL];
            o *= inv;
        }
        attnb[((size_t)b * SEQ + qt * QROWS + row) * DMODEL + h * HDIM + l] = f2bf(o);
    }
}

// ---------------------------------------------------------------------------
extern "C" void kernel_launch(void* const* d_in, const int* in_sizes, int n_in,
                              void* d_out, int out_size, void* d_ws, size_t ws_size,
                              hipStream_t stream) {
    const float* Q  = (const float*)d_in[0];
    const float* K  = (const float*)d_in[1];
    const float* V  = (const float*)d_in[2];
    const float* Wq = (const float*)d_in[3];
    const float* bq = (const float*)d_in[4];
    const float* Wk = (const float*)d_in[5];
    const float* bk = (const float*)d_in[6];
    const float* Wv = (const float*)d_in[7];
    const float* bv = (const float*)d_in[8];
    const float* Wo = (const float*)d_in[9];
    const float* bo = (const float*)d_in[10];

    const size_t PLANE  = (size_t)MROWS * DMODEL;     // 4 Mi elements
    const size_t WPLANE = (size_t)DMODEL * DMODEL;

    // Workspace layout (90 MiB total):
    unsigned short* R1 = (unsigned short*)d_ws;        // 2P: V split (1P) -> Q split -> attnb
    unsigned short* R2 = R1 + 2 * PLANE;               // 2P: K split
    unsigned short* W1 = R2 + 2 * PLANE;               // 1W: Wv, later Wo
    unsigned short* W2 = W1 + WPLANE;                  // 2W: Wq planes
    unsigned short* W3 = W2 + 2 * WPLANE;              // 2W: Wk planes
    unsigned short* q3 = W3 + 2 * WPLANE;              // 2P
    unsigned short* k3 = q3 + 2 * PLANE;               // 2P
    float*          vf = (float*)(k3 + 2 * PLANE);     // PLANE f32
    unsigned short* attnb = R1;                        // reuse after QK GEMM

    dim3 blk(256, 1, 1);
    const int nvec = (int)(PLANE / 8);
    dim3 gs((nvec + 255) / 256, 1, 1);
    dim3 gs2((nvec + 255) / 256, 2, 1);
    dim3 gw(DMODEL / 64, DMODEL / 64, 1);
    dim3 gw2(DMODEL / 64, DMODEL / 64, 2);
    dim3 gg(DMODEL / 64, MROWS / 128, 1);              // 512 blocks (NS=1)
    dim3 gg2(DMODEL / 64, MROWS / 128, 2);             // 1024 blocks (merged Q+K)

    // ---- V projection first (frees R1 for Q split) ----
    splitx_k<1, false><<<gs, blk, 0, stream>>>(V, R1, nullptr, nullptr, nvec, PLANE);
    wsplit_k<1, false><<<gw, blk, 0, stream>>>(Wv, W1, nullptr, nullptr, WPLANE);
    gemm_planes<1, false, false, false><<<gg, blk, 0, stream>>>(
        R1, W1, bv, vf, nullptr, 1.0f,
        nullptr, nullptr, nullptr, nullptr, 0.f,
        MROWS, DMODEL, DMODEL, PLANE, WPLANE, PLANE);

    // ---- Q+K splits and projections, merged dispatches ----
    splitx_k<2, true><<<gs2, blk, 0, stream>>>(Q, R1, K, R2, nvec, PLANE);
    wsplit_k<2, true><<<gw2, blk, 0, stream>>>(Wq, W2, Wk, W3, WPLANE);
    gemm_planes<2, true, true, true><<<gg2, blk, 0, stream>>>(
        R1, W2, bq, nullptr, q3, 0.125f,
        R2, W3, bk, k3, 1.0f,
        MROWS, DMODEL, DMODEL, PLANE, WPLANE, PLANE);

    // ---- fused masked attention (single pass) -> bf16 attnb ----
    attn_k<<<dim3(64 * 8, 1, 1), dim3(512, 1, 1), 0, stream>>>(q3, k3, vf, attnb, PLANE);

    // ---- O projection (plain bf16 MFMA) -> fp32 d_out ----
    wsplit_k<1, false><<<gw, blk, 0, stream>>>(Wo, W1, nullptr, nullptr, WPLANE);
    gemm_planes<1, false, false, false><<<gg, blk, 0, stream>>>(
        attnb, W1, bo, (float*)d_out, nullptr, 1.0f,
        nullptr, nullptr, nullptr, nullptr, 0.f,
        MROWS, DMODEL, DMODEL, PLANE, WPLANE, PLANE);
}

// Round 14
// 285.832 us; speedup vs baseline: 1.3319x; 1.0084x over previous
//
#include <hip/hip_runtime.h>
#include <hip/hip_bf16.h>
#include <math.h>

// Problem constants (B=4, S=1024, D=1024, H=16, hd=64)
#define SEQ    1024
#define DMODEL 1024
#define NHEAD  16
#define HDIM   64
#define BATCH  4
#define MROWS  4096   // B*S

typedef float f32x4 __attribute__((ext_vector_type(4)));
typedef short s16x8 __attribute__((ext_vector_type(8)));
typedef _Float16 f16x8 __attribute__((ext_vector_type(8)));

__device__ __forceinline__ float bf2f(unsigned short u) {
    return __uint_as_float(((unsigned int)u) << 16);
}
__device__ __forceinline__ unsigned short f2bf(float f) {
    __hip_bfloat16 h = __float2bfloat16(f);   // RNE
    return *reinterpret_cast<unsigned short*>(&h);
}
// fp16 helpers (RNE)
__device__ __forceinline__ unsigned short f2h(float f) {
    _Float16 h = (_Float16)f;
    return *reinterpret_cast<unsigned short*>(&h);
}
__device__ __forceinline__ float h2f(unsigned short u) {
    _Float16 h = *reinterpret_cast<_Float16*>(&u);
    return (float)h;
}
// scaled fp16 split-2: x ~= h0 + h1 * 2^-11,  h1 stored PRE-SCALED by 2048
// so residuals stay in fp16 normal range. Representation error ~1.2e-7 |x|.
__device__ __forceinline__ void split2(float x, unsigned short& u0, unsigned short& u1) {
    u0 = f2h(x);
    float f0 = h2f(u0);
    u1 = f2h((x - f0) * 2048.0f);
}

// async global->LDS, 16B per lane, dest = wave-uniform base + lane*16
__device__ __forceinline__ void gload16(const void* g, void* l) {
    __builtin_amdgcn_global_load_lds(
        (const __attribute__((address_space(1))) unsigned int*)g,
        (__attribute__((address_space(3))) unsigned int*)l, 16, 0, 0);
}

// ---------------------------------------------------------------------------
// Input split: X[n] fp32 -> planes.
//   NS=1: single bf16 plane.   NS=2: fp16 split-2 planes (h1 pre-scaled 2048).
// DUAL: blockIdx.y selects (X0->P0) vs (X1->P1) -- Q and K in one dispatch.
// ---------------------------------------------------------------------------
template<int NS, bool DUAL>
__global__ __launch_bounds__(256) void splitx_k(const float* __restrict__ X0,
                                                unsigned short* __restrict__ P0,
                                                const float* __restrict__ X1,
                                                unsigned short* __restrict__ P1,
                                                int nvec, size_t plane)
{
    const float* X = X0;
    unsigned short* P = P0;
    if constexpr (DUAL) { if (blockIdx.y) { X = X1; P = P1; } }
    const int i = blockIdx.x * 256 + threadIdx.x;   // 8-element vector index
    if (i >= nvec) return;
    const float* src = X + (size_t)i * 8;
    float4 v0 = *(const float4*)src;
    float4 v1 = *(const float4*)(src + 4);
    float x[8] = {v0.x, v0.y, v0.z, v0.w, v1.x, v1.y, v1.z, v1.w};
    unsigned short p0[8], p1[8];
    #pragma unroll
    for (int e = 0; e < 8; ++e) {
        if (NS == 1) { p0[e] = f2bf(x[e]); }
        else         { split2(x[e], p0[e], p1[e]); }
    }
    *(uint4*)(P + (size_t)i * 8) = *(uint4*)p0;
    if (NS == 2) {
        *(uint4*)(P + plane + (size_t)i * 8) = *(uint4*)p1;
    }
}

// ---------------------------------------------------------------------------
// Weight split+transpose: W[K][N] fp32 -> NS planes Wt[p][N][K].
// DUAL: blockIdx.z selects (W0->Wt0) vs (W1->Wt1).
// ---------------------------------------------------------------------------
template<int NS, bool DUAL>
__global__ __launch_bounds__(256) void wsplit_k(const float* __restrict__ W0,
                                                unsigned short* __restrict__ Wt0,
                                                const float* __restrict__ W1,
                                                unsigned short* __restrict__ Wt1,
                                                size_t plane)
{
    const float* W = W0;
    unsigned short* Wt = Wt0;
    if constexpr (DUAL) { if (blockIdx.z) { W = W1; Wt = Wt1; } }
    __shared__ float tile[64][65];
    const int t  = threadIdx.x;
    const int n0 = blockIdx.x * 64;
    const int k0 = blockIdx.y * 64;
    const int col = t & 63;
    const int rq  = t >> 6;

    #pragma unroll
    for (int p = 0; p < 16; ++p) {
        const int row = p * 4 + rq;                      // k-local
        tile[row][col] = W[(size_t)(k0 + row) * DMODEL + n0 + col];
    }
    __syncthreads();
    #pragma unroll
    for (int p = 0; p < 16; ++p) {
        const int nrow = p * 4 + rq;                     // n-local
        const float v = tile[col][nrow];                 // = W[k0+col][n0+nrow]
        const size_t o = (size_t)(n0 + nrow) * DMODEL + k0 + col;
        if (NS == 1) {
            Wt[o] = f2bf(v);
        } else {
            unsigned short u0, u1;
            split2(v, u0, u1);
            Wt[o] = u0; Wt[plane + o] = u1;
        }
    }
}

// ---------------------------------------------------------------------------
// MFMA GEMM on pre-split planes: C = A @ W^T + bias.
// 256-thread blocks (4 waves), BM=128 BN=64 BK=32; each wave a 64x32 sub-tile
// (4x2 frags of 16x16). LDS S[2][NS][192][32] = 48KB (NS=2) / 24KB (NS=1).
// T4 counted-vmcnt pipeline (vmcnt(6)/vmcnt(3), 0 only on last K-step);
// sched_barrier(0) pins (rule #18); T5 setprio around MFMA cluster.
// DUAL (Q+K merged): blockIdx.z selects problem -> 1024 blocks, 3 blocks/CU.
// T1 chunked XCD swizzle: swz=(bid&7)*64+(bid>>3) -> each XCD owns 4
// contiguous m-panels (A-panel fetched into exactly one L2). BIT-IDENTICAL.
//
// NS=2 (fp16 split-2) hierarchical f32 fold:
//   zacc[f] = mfma(P0a, P0b, zacc[f])  -- inner chain, 4 K-steps
//   every 4 steps: macc[f] += zacc[f]; zacc[f]=0  (f32 outer, no fp64 array
//   -> 96 live regs, no spill).  facc += P0a*P1b' + P1a'*P0b (2048-scaled,
//   descaled 2^-11 at epilogue).
// ---------------------------------------------------------------------------
template<int NS, bool FOLD, bool SPLITOUT, bool DUAL>
__global__ __launch_bounds__(256, (NS == 1 ? 4 : 3))
void gemm_planes(const unsigned short* Ab0, const unsigned short* Bb0,
                 const float* bias0, float* __restrict__ Cp,
                 unsigned short* Pout0, float oscale0,
                 const unsigned short* Ab1, const unsigned short* Bb1,
                 const float* bias1, unsigned short* Pout1, float oscale1,
                 int M, int N, int K,
                 size_t planeA, size_t planeB, size_t planeO)
{
    const unsigned short* Ab = Ab0;
    const unsigned short* Bb = Bb0;
    const float* biasp = bias0;
    unsigned short* Pout = Pout0;
    float oscale = oscale0;
    if constexpr (DUAL) {
        if (blockIdx.z) { Ab = Ab1; Bb = Bb1; biasp = bias1; Pout = Pout1; oscale = oscale1; }
    }

    // T1 chunked XCD swizzle (bijective since nwg = 16*32 = 512, 512%8==0)
    const int nbx = gridDim.x;
    const int nwg = nbx * gridDim.y;          // 512
    int bid = blockIdx.y * nbx + blockIdx.x;
    bid = (bid & 7) * (nwg >> 3) + (bid >> 3);
    const int m0 = (bid / nbx) * 128;
    const int n0 = (bid % nbx) * 64;

    // rows 0..127 = A-tile, rows 128..191 = B-tile
    __shared__ unsigned short S[2][NS][192][32];

    const int t = threadIdx.x;
    const int w = t >> 6, l = t & 63, g = l >> 4, j = l & 15;
    const int wm = w >> 1;          // 0..1  (M direction, 64 rows each)
    const int wn = w & 1;           // 0..1  (N direction, 32 cols each)

    f32x4 facc[8];
    f32x4 zacc[8];
    f32x4 macc[8];
    #pragma unroll
    for (int f = 0; f < 8; ++f) {
        facc[f] = (f32x4){0.f, 0.f, 0.f, 0.f};
        zacc[f] = (f32x4){0.f, 0.f, 0.f, 0.f};
        macc[f] = (f32x4){0.f, 0.f, 0.f, 0.f};
    }

    // staging geometry: wave w stages rows [w*16, w*16+16) of each 64-row
    // chunk; lane -> row l>>2, source col-granule (l&3) ^ ((l>>3)&3)
    // (pre-swizzled global source; LDS dest linear per gload_lds rule).
    const int stgrow = w * 16 + (l >> 2);
    const int stgcol = ((l & 3) ^ ((l >> 3) & 3)) * 8;
    const unsigned short* gA = Ab + (size_t)(m0 + stgrow) * K + stgcol;
    const unsigned short* gB = Bb + (size_t)(n0 + stgrow) * K + stgcol;

    auto stage = [&](int buf, int k0) {
        #pragma unroll
        for (int p = 0; p < NS; ++p) {
            gload16(gA + (size_t)p * planeA + k0,                  &S[buf][p][w * 16][0]);
            gload16(gA + (size_t)p * planeA + (size_t)64 * K + k0, &S[buf][p][64 + w * 16][0]);
            gload16(gB + (size_t)p * planeB + k0,                  &S[buf][p][128 + w * 16][0]);
        }
    };

    // swizzled fragment column (elements): matches the staging swizzle
    const int gs8 = (g ^ ((j >> 1) & 3)) * 8;

    stage(0, 0);
    const int NT = K / 32;
    for (int kt = 0; kt < NT; ++kt) {
        const int cur = kt & 1;
        if (kt + 1 < NT) {
            stage(cur ^ 1, (kt + 1) * 32);   // issue next tile: stays in flight
            if constexpr (NS == 2) asm volatile("s_waitcnt vmcnt(6)" ::: "memory");
            else                   asm volatile("s_waitcnt vmcnt(3)" ::: "memory");
        } else {
            asm volatile("s_waitcnt vmcnt(0)" ::: "memory");
        }
        __builtin_amdgcn_sched_barrier(0);
        __builtin_amdgcn_s_barrier();        // buf[cur] ready on all waves
        __builtin_amdgcn_sched_barrier(0);

        if constexpr (NS == 1) {
            s16x8 a[4];
            #pragma unroll
            for (int mi = 0; mi < 4; ++mi)
                a[mi] = *(const s16x8*)&S[cur][0][wm * 64 + mi * 16 + j][gs8];
            __builtin_amdgcn_s_setprio(1);
            #pragma unroll
            for (int ni = 0; ni < 2; ++ni) {
                const int nr = 128 + wn * 32 + ni * 16 + j;
                s16x8 b0 = *(const s16x8*)&S[cur][0][nr][gs8];
                #pragma unroll
                for (int mi = 0; mi < 4; ++mi) {
                    const int f = mi * 2 + ni;
                    facc[f] = __builtin_amdgcn_mfma_f32_16x16x32_bf16(a[mi], b0, facc[f], 0, 0, 0);
                }
            }
            __builtin_amdgcn_s_setprio(0);
        } else {
            f16x8 a0[4], a1[4];
            #pragma unroll
            for (int mi = 0; mi < 4; ++mi) {
                a0[mi] = *(const f16x8*)&S[cur][0][wm * 64 + mi * 16 + j][gs8];
                a1[mi] = *(const f16x8*)&S[cur][1][wm * 64 + mi * 16 + j][gs8];
            }
            __builtin_amdgcn_s_setprio(1);
            #pragma unroll
            for (int ni = 0; ni < 2; ++ni) {
                const int nr = 128 + wn * 32 + ni * 16 + j;
                f16x8 b0 = *(const f16x8*)&S[cur][0][nr][gs8];
                f16x8 b1 = *(const f16x8*)&S[cur][1][nr][gs8];
                #pragma unroll
                for (int mi = 0; mi < 4; ++mi) {
                    const int f = mi * 2 + ni;
                    zacc[f] = __builtin_amdgcn_mfma_f32_16x16x32_f16(a0[mi], b0, zacc[f], 0, 0, 0);
                    facc[f] = __builtin_amdgcn_mfma_f32_16x16x32_f16(a0[mi], b1, facc[f], 0, 0, 0);
                    facc[f] = __builtin_amdgcn_mfma_f32_16x16x32_f16(a1[mi], b0, facc[f], 0, 0, 0);
                }
            }
            __builtin_amdgcn_s_setprio(0);
            // hierarchical fold: f32 outer accumulate every 4 K-steps
            if ((kt & 3) == 3 || kt == NT - 1) {
                #pragma unroll
                for (int f = 0; f < 8; ++f) {
                    macc[f] += zacc[f];
                    zacc[f] = (f32x4){0.f, 0.f, 0.f, 0.f};
                }
            }
        }

        __builtin_amdgcn_sched_barrier(0);
        __builtin_amdgcn_s_barrier();        // all reads of buf[cur] done
        __builtin_amdgcn_sched_barrier(0);
    }

    #pragma unroll
    for (int ni = 0; ni < 2; ++ni) {
        const int col = n0 + wn * 32 + ni * 16 + j;
        const float bv = biasp[col];
        #pragma unroll
        for (int mi = 0; mi < 4; ++mi) {
            const int f = mi * 2 + ni;
            #pragma unroll
            for (int r = 0; r < 4; ++r) {
                const int row = m0 + wm * 64 + mi * 16 + 4 * g + r;
                float val;
                if (FOLD) val = (float)((double)macc[f][r] + (double)facc[f][r] * (1.0 / 2048.0) + (double)bv);
                else      val = facc[f][r] + bv;
                if (SPLITOUT) {
                    const int bq = row >> 10, s = row & 1023;
                    const int h  = col >> 6,  d = col & 63;
                    const size_t o = (((size_t)(bq * 16 + h)) * SEQ + s) * HDIM + d;
                    unsigned short u0, u1;
                    split2(val * oscale, u0, u1);
                    Pout[o] = u0; Pout[planeO + o] = u1;
                } else {
                    Cp[(size_t)row * N + col] = val;
                }
            }
        }
    }
}

// ---------------------------------------------------------------------------
// Fused attention, single-pass: 128 q-rows/block (8 waves, one 16-row q-tile
// per wave), K chunks staged in LDS and shared by all 8 waves.
// q3/k3 are fp16 split-2 planes:
//   score = accM + (accC0+accC1) * 2^-11   (6 MFMAs/kb)
// T14 async-STAGE split: chunk ch+1's global loads issued right after the
// stage barrier of ch, consumed at the next iteration's ds_write.
//
// R14: Z-from-candidates. The mask-Z at TEMP=0.001 gets < e^-32 from any
// key with s < m-0.032, so Z is computed at FINALIZE from the captured
// candidates only (capture widened to thr = rm-0.032, superset of both
// survivors [cut >= m-0.004] and all Z-relevant terms). The per-chunk
// online-Z exp machinery (5 expf + rescale per (chunk,r)) is DELETED --
// chunk loop now does only max-reduce + capture. Z error ~1e-10 rel.
// Dead-exp skip kept (skip when all chunk scores < rm-0.033 < thr).
// CAND 32->40 (E[cand] ~8 at sigma~1; overflow hits the visible INFINITY
// sentinel, not silent). LDS ~58 KB -> 2 blocks/CU.
// ---------------------------------------------------------------------------
#define CAND 40
#define QROWS 128
__global__ __launch_bounds__(512, 4) void attn_k(const unsigned short* __restrict__ q3,
                                                 const unsigned short* __restrict__ k3,
                                                 const float* __restrict__ vf,
                                                 unsigned short* __restrict__ attnb,
                                                 size_t plane)
{
    __shared__ unsigned short Ks[2][64][72];   // 18.4 KB
    __shared__ int   ckey[QROWS][CAND];        // 20 KB
    __shared__ float csc[QROWS][CAND];         // 20 KB
    __shared__ int   ccnt[QROWS];
    __shared__ float zinv[QROWS];

    const int t  = threadIdx.x;
    const int w  = t >> 6, l = t & 63, g = l >> 4, j = l & 15;
    const int bh = blockIdx.x >> 3;     // 0..63
    const int qt = blockIdx.x & 7;      // 0..7 (128-row q groups)
    const int b  = bh >> 4, h = bh & 15;

    if (t < QROWS) ccnt[t] = 0;

    // A-frags for this wave's 16 q-rows (q pre-scaled 1/8 in planes)
    f16x8 aq[2][2];
    {
        const size_t qoff = ((size_t)bh * SEQ + qt * QROWS + w * 16 + j) * HDIM + g * 8;
        #pragma unroll
        for (int p = 0; p < 2; ++p)
            #pragma unroll
            for (int half = 0; half < 2; ++half)
                aq[p][half] = *(const f16x8*)(q3 + p * plane + qoff + half * 32);
    }

    // staging: 512 threads, each one uint4 (8 elems) per plane
    const int skey = t >> 3;            // staging key-local 0..63
    const int soff = (t & 7) * 8;       // element offset 0..56
    const unsigned short* ksrc = k3 + (size_t)bh * (SEQ * HDIM) + (size_t)skey * HDIM + soff;

    float rm[4];
    #pragma unroll
    for (int r = 0; r < 4; ++r) rm[r] = -INFINITY;

    // T14 prologue: chunk 0 loads in flight before the loop
    uint4 stg0 = *(const uint4*)(ksrc);
    uint4 stg1 = *(const uint4*)(ksrc + plane);

    for (int ch = 0; ch < 16; ++ch) {
        __syncthreads();                      // Ks free (prev readers done)
        *(uint4*)&Ks[0][skey][soff] = stg0;
        *(uint4*)&Ks[1][skey][soff] = stg1;
        __syncthreads();                      // Ks ready
        // issue next chunk's loads now; consumed at next iteration's ds_write
        if (ch + 1 < 16) {
            const unsigned short* s = ksrc + (ch + 1) * 4096;
            stg0 = *(const uint4*)(s);
            stg1 = *(const uint4*)(s + plane);
        }

        float sc[4][4];   // [kb][r]
        __builtin_amdgcn_s_setprio(1);
        #pragma unroll
        for (int kb = 0; kb < 4; ++kb) {
            f32x4 accM = {0.f,0.f,0.f,0.f};
            f32x4 accC0 = {0.f,0.f,0.f,0.f}, accC1 = {0.f,0.f,0.f,0.f};
            const int kr = kb * 16 + j;
            #pragma unroll
            for (int half = 0; half < 2; ++half) {
                f16x8 b0 = *(const f16x8*)&Ks[0][kr][half * 32 + g * 8];
                f16x8 b1 = *(const f16x8*)&Ks[1][kr][half * 32 + g * 8];
                accM  = __builtin_amdgcn_mfma_f32_16x16x32_f16(aq[0][half], b0, accM,  0, 0, 0);
                accC0 = __builtin_amdgcn_mfma_f32_16x16x32_f16(aq[0][half], b1, accC0, 0, 0, 0);
                accC1 = __builtin_amdgcn_mfma_f32_16x16x32_f16(aq[1][half], b0, accC1, 0, 0, 0);
            }
            #pragma unroll
            for (int r = 0; r < 4; ++r)
                sc[kb][r] = accM[r] + (accC0[r] + accC1[r]) * (1.0f / 2048.0f);
        }
        __builtin_amdgcn_s_setprio(0);

        // running max + candidate capture (NO online Z -- R14)
        #pragma unroll
        for (int r = 0; r < 4; ++r) {
            float nmc = fmaxf(fmaxf(sc[0][r], sc[1][r]), fmaxf(sc[2][r], sc[3][r]));
            #pragma unroll
            for (int off = 1; off < 16; off <<= 1) nmc = fmaxf(nmc, __shfl_xor(nmc, off));
            // skip: all chunk scores < rm-0.033 < thr -> no capture possible,
            // and their Z terms are < e^-33 (sub-1e-14). Wave-uniform branch.
            if (__all(nmc <= rm[r] - 0.033f)) continue;
            rm[r] = fmaxf(nmc, rm[r]);
            const float thr = rm[r] - 0.032f;  // superset of survivors AND
                                               // of all Z-relevant terms
            #pragma unroll
            for (int kb = 0; kb < 4; ++kb) {
                if (sc[kb][r] >= thr) {
                    const int row = w * 16 + 4 * g + r;
                    const int pos = atomicAdd(&ccnt[row], 1);
                    if (pos < CAND) {
                        ckey[row][pos] = ch * 64 + kb * 16 + j;
                        csc[row][pos]  = sc[kb][r];
                    }
                }
            }
        }
    }
    __syncthreads();

    // finalize: Z from candidates (pass 1), exact fp64 cut, prune (pass 2)
    #pragma unroll
    for (int r = 0; r < 4; ++r) {
        if (j == r) {
            const int row = w * 16 + 4 * g + r;
            const int craw = ccnt[row];
            const int c = craw < CAND ? craw : CAND;
            float zm = 0.f;
            for (int i = 0; i < c; ++i)
                zm += __expf((csc[row][i] - rm[r]) * 1000.f);
            const double cut = (double)rm[r] + 0.001 * log(0.019 * (double)zm);
            int n = 0; float z2 = 0.f;
            for (int i = 0; i < c; ++i) {
                const float s = csc[row][i];
                if ((double)s >= cut) {
                    const float ev = __expf(s - rm[r]);
                    ckey[row][n] = ckey[row][i];
                    csc[row][n]  = ev;
                    z2 += ev; ++n;
                }
            }
            ccnt[row] = (craw > CAND) ? -1 : n;   // -1 = overflow sentinel
            zinv[row] = (n > 0) ? 1.f / z2 : 0.f;
        }
    }
    __syncthreads();

    // sparse PV gather (wave w handles its own 16 rows; lane l = dim).
    // 4-way load batching; fmac order matches the serial loop.
    const float* vbase = vf + (size_t)b * SEQ * DMODEL + h * HDIM + l;
    for (int i = 0; i < 16; ++i) {
        const int row = w * 16 + i;
        const int n = ccnt[row];
        float o = 0.f;
        if (n == 0) {
            // all masked -> uniform weights over all 1024 keys
            for (int kk = 0; kk < SEQ; ++kk) o += vbase[(size_t)kk * DMODEL];
            o *= (1.0f / 1024.0f);
        } else if (n < 0) {
            o = INFINITY;   // candidate overflow sentinel (visible failure)
        } else {
            const float inv = zinv[row];
            int i2 = 0;
            for (; i2 + 4 <= n; i2 += 4) {
                const float c0 = csc[row][i2 + 0], c1 = csc[row][i2 + 1];
                const float c2 = csc[row][i2 + 2], c3 = csc[row][i2 + 3];
                const float v0 = vbase[(size_t)ckey[row][i2 + 0] * DMODEL];
                const float v1 = vbase[(size_t)ckey[row][i2 + 1] * DMODEL];
                const float v2 = vbase[(size_t)ckey[row][i2 + 2] * DMODEL];
                const float v3 = vbase[(size_t)ckey[row][i2 + 3] * DMODEL];
                o += c0 * v0; o += c1 * v1; o += c2 * v2; o += c3 * v3;
            }
            for (; i2 < n; ++i2)
                o += csc[row][i2] * vbase[(size_t)ckey[row][i2] * DMODEL];
            o *= inv;
        }
        attnb[((size_t)b * SEQ + qt * QROWS + row) * DMODEL + h * HDIM + l] = f2bf(o);
    }
}

// ---------------------------------------------------------------------------
extern "C" void kernel_launch(void* const* d_in, const int* in_sizes, int n_in,
                              void* d_out, int out_size, void* d_ws, size_t ws_size,
                              hipStream_t stream) {
    const float* Q  = (const float*)d_in[0];
    const float* K  = (const float*)d_in[1];
    const float* V  = (const float*)d_in[2];
    const float* Wq = (const float*)d_in[3];
    const float* bq = (const float*)d_in[4];
    const float* Wk = (const float*)d_in[5];
    const float* bk = (const float*)d_in[6];
    const float* Wv = (const float*)d_in[7];
    const float* bv = (const float*)d_in[8];
    const float* Wo = (const float*)d_in[9];
    const float* bo = (const float*)d_in[10];

    const size_t PLANE  = (size_t)MROWS * DMODEL;     // 4 Mi elements
    const size_t WPLANE = (size_t)DMODEL * DMODEL;

    // Workspace layout (90 MiB total):
    unsigned short* R1 = (unsigned short*)d_ws;        // 2P: V split (1P) -> Q split -> attnb
    unsigned short* R2 = R1 + 2 * PLANE;               // 2P: K split
    unsigned short* W1 = R2 + 2 * PLANE;               // 1W: Wv, later Wo
    unsigned short* W2 = W1 + WPLANE;                  // 2W: Wq planes
    unsigned short* W3 = W2 + 2 * WPLANE;              // 2W: Wk planes
    unsigned short* q3 = W3 + 2 * WPLANE;              // 2P
    unsigned short* k3 = q3 + 2 * PLANE;               // 2P
    float*          vf = (float*)(k3 + 2 * PLANE);     // PLANE f32
    unsigned short* attnb = R1;                        // reuse after QK GEMM

    dim3 blk(256, 1, 1);
    const int nvec = (int)(PLANE / 8);
    dim3 gs((nvec + 255) / 256, 1, 1);
    dim3 gs2((nvec + 255) / 256, 2, 1);
    dim3 gw(DMODEL / 64, DMODEL / 64, 1);
    dim3 gw2(DMODEL / 64, DMODEL / 64, 2);
    dim3 gg(DMODEL / 64, MROWS / 128, 1);              // 512 blocks (NS=1)
    dim3 gg2(DMODEL / 64, MROWS / 128, 2);             // 1024 blocks (merged Q+K)

    // ---- V projection first (frees R1 for Q split) ----
    splitx_k<1, false><<<gs, blk, 0, stream>>>(V, R1, nullptr, nullptr, nvec, PLANE);
    wsplit_k<1, false><<<gw, blk, 0, stream>>>(Wv, W1, nullptr, nullptr, WPLANE);
    gemm_planes<1, false, false, false><<<gg, blk, 0, stream>>>(
        R1, W1, bv, vf, nullptr, 1.0f,
        nullptr, nullptr, nullptr, nullptr, 0.f,
        MROWS, DMODEL, DMODEL, PLANE, WPLANE, PLANE);

    // ---- Q+K splits and projections, merged dispatches ----
    splitx_k<2, true><<<gs2, blk, 0, stream>>>(Q, R1, K, R2, nvec, PLANE);
    wsplit_k<2, true><<<gw2, blk, 0, stream>>>(Wq, W2, Wk, W3, WPLANE);
    gemm_planes<2, true, true, true><<<gg2, blk, 0, stream>>>(
        R1, W2, bq, nullptr, q3, 0.125f,
        R2, W3, bk, k3, 1.0f,
        MROWS, DMODEL, DMODEL, PLANE, WPLANE, PLANE);

    // ---- fused masked attention (single pass) -> bf16 attnb ----
    attn_k<<<dim3(64 * 8, 1, 1), dim3(512, 1, 1), 0, stream>>>(q3, k3, vf, attnb, PLANE);

    // ---- O projection (plain bf16 MFMA) -> fp32 d_out ----
    wsplit_k<1, false><<<gw, blk, 0, stream>>>(Wo, W1, nullptr, nullptr, WPLANE);
    gemm_planes<1, false, false, false><<<gg, blk, 0, stream>>>(
        attnb, W1, bo, (float*)d_out, nullptr, 1.0f,
        nullptr, nullptr, nullptr, nullptr, 0.f,
        MROWS, DMODEL, DMODEL, PLANE, WPLANE, PLANE);
}

// Round 16
// 284.344 us; speedup vs baseline: 1.3389x; 1.0052x over previous
//
#include <hip/hip_runtime.h>
#include <hip/hip_bf16.h>
#include <math.h>

// Problem constants (B=4, S=1024, D=1024, H=16, hd=64)
#define SEQ    1024
#define DMODEL 1024
#define NHEAD  16
#define HDIM   64
#define BATCH  4
#define MROWS  4096   // B*S

typedef float f32x4 __attribute__((ext_vector_type(4)));
typedef short s16x8 __attribute__((ext_vector_type(8)));
typedef _Float16 f16x8 __attribute__((ext_vector_type(8)));

__device__ __forceinline__ float bf2f(unsigned short u) {
    return __uint_as_float(((unsigned int)u) << 16);
}
__device__ __forceinline__ unsigned short f2bf(float f) {
    __hip_bfloat16 h = __float2bfloat16(f);   // RNE
    return *reinterpret_cast<unsigned short*>(&h);
}
// fp16 helpers (RNE)
__device__ __forceinline__ unsigned short f2h(float f) {
    _Float16 h = (_Float16)f;
    return *reinterpret_cast<unsigned short*>(&h);
}
__device__ __forceinline__ float h2f(unsigned short u) {
    _Float16 h = *reinterpret_cast<_Float16*>(&u);
    return (float)h;
}
// scaled fp16 split-2: x ~= h0 + h1 * 2^-11,  h1 stored PRE-SCALED by 2048
// so residuals stay in fp16 normal range. Representation error ~1.2e-7 |x|.
__device__ __forceinline__ void split2(float x, unsigned short& u0, unsigned short& u1) {
    u0 = f2h(x);
    float f0 = h2f(u0);
    u1 = f2h((x - f0) * 2048.0f);
}

// async global->LDS, 16B per lane, dest = wave-uniform base + lane*16
__device__ __forceinline__ void gload16(const void* g, void* l) {
    __builtin_amdgcn_global_load_lds(
        (const __attribute__((address_space(1))) unsigned int*)g,
        (__attribute__((address_space(3))) unsigned int*)l, 16, 0, 0);
}

// ---------------------------------------------------------------------------
// prep_split: ONE dispatch for all three input splits (dispatch-count
// reduction; ~10us/boundary launch overhead was the largest unclaimed cost).
// blockIdx.y: 0 -> Q fp16-split2 into PQ,PQ+plane; 1 -> K into PK;
//             2 -> V bf16 single plane into PV.
// Same per-element conversions as before -> outputs BIT-IDENTICAL.
// ---------------------------------------------------------------------------
__global__ __launch_bounds__(256) void prep_split(const float* __restrict__ Q,
                                                  unsigned short* __restrict__ PQ,
                                                  const float* __restrict__ K,
                                                  unsigned short* __restrict__ PK,
                                                  const float* __restrict__ V,
                                                  unsigned short* __restrict__ PV,
                                                  int nvec, size_t plane)
{
    const int which = blockIdx.y;
    const float* X = (which == 0) ? Q : (which == 1) ? K : V;
    unsigned short* P = (which == 0) ? PQ : (which == 1) ? PK : PV;
    const int i = blockIdx.x * 256 + threadIdx.x;   // 8-element vector index
    if (i >= nvec) return;
    const float* src = X + (size_t)i * 8;
    float4 v0 = *(const float4*)src;
    float4 v1 = *(const float4*)(src + 4);
    float x[8] = {v0.x, v0.y, v0.z, v0.w, v1.x, v1.y, v1.z, v1.w};
    unsigned short p0[8], p1[8];
    if (which < 2) {
        #pragma unroll
        for (int e = 0; e < 8; ++e) split2(x[e], p0[e], p1[e]);
        *(uint4*)(P + (size_t)i * 8)         = *(uint4*)p0;
        *(uint4*)(P + plane + (size_t)i * 8) = *(uint4*)p1;
    } else {
        #pragma unroll
        for (int e = 0; e < 8; ++e) p0[e] = f2bf(x[e]);
        *(uint4*)(P + (size_t)i * 8) = *(uint4*)p0;
    }
}

// ---------------------------------------------------------------------------
// prep_wsplit: ONE dispatch for all four weight split+transposes.
// blockIdx.z: 0 -> Wq (fp16 split2), 1 -> Wk (split2),
//             2 -> Wv (bf16), 3 -> Wo (bf16).
// W[K][N] fp32 -> Wt[N][K] planes. Outputs BIT-IDENTICAL to before.
// ---------------------------------------------------------------------------
__global__ __launch_bounds__(256) void prep_wsplit(const float* __restrict__ Wq,
                                                   unsigned short* __restrict__ Tq,
                                                   const float* __restrict__ Wk,
                                                   unsigned short* __restrict__ Tk,
                                                   const float* __restrict__ Wv,
                                                   unsigned short* __restrict__ Tv,
                                                   const float* __restrict__ Wo,
                                                   unsigned short* __restrict__ To,
                                                   size_t plane)
{
    const int z = blockIdx.z;
    const float* W = (z == 0) ? Wq : (z == 1) ? Wk : (z == 2) ? Wv : Wo;
    unsigned short* Wt = (z == 0) ? Tq : (z == 1) ? Tk : (z == 2) ? Tv : To;
    const bool ns2 = (z < 2);

    __shared__ float tile[64][65];
    const int t  = threadIdx.x;
    const int n0 = blockIdx.x * 64;
    const int k0 = blockIdx.y * 64;
    const int col = t & 63;
    const int rq  = t >> 6;

    #pragma unroll
    for (int p = 0; p < 16; ++p) {
        const int row = p * 4 + rq;                      // k-local
        tile[row][col] = W[(size_t)(k0 + row) * DMODEL + n0 + col];
    }
    __syncthreads();
    #pragma unroll
    for (int p = 0; p < 16; ++p) {
        const int nrow = p * 4 + rq;                     // n-local
        const float v = tile[col][nrow];                 // = W[k0+col][n0+nrow]
        const size_t o = (size_t)(n0 + nrow) * DMODEL + k0 + col;
        if (ns2) {
            unsigned short u0, u1;
            split2(v, u0, u1);
            Wt[o] = u0; Wt[plane + o] = u1;
        } else {
            Wt[o] = f2bf(v);
        }
    }
}

// ---------------------------------------------------------------------------
// MFMA GEMM on pre-split planes: C = A @ W^T + bias.  (UNCHANGED from R14)
// 256-thread blocks (4 waves), BM=128 BN=64 BK=32; each wave a 64x32 sub-tile
// (4x2 frags of 16x16). LDS S[2][NS][192][32] = 48KB (NS=2) / 24KB (NS=1).
// T4 counted-vmcnt pipeline; sched_barrier(0) pins; T5 setprio.
// DUAL (Q+K merged): blockIdx.z selects problem -> 1024 blocks, 3 blocks/CU.
// T1 chunked XCD swizzle. NS=2 hierarchical f32 fold (zacc->macc every 4
// K-steps); facc carries cross terms (2048-scaled, descaled at epilogue).
// ---------------------------------------------------------------------------
template<int NS, bool FOLD, bool SPLITOUT, bool DUAL>
__global__ __launch_bounds__(256, (NS == 1 ? 4 : 3))
void gemm_planes(const unsigned short* Ab0, const unsigned short* Bb0,
                 const float* bias0, float* __restrict__ Cp,
                 unsigned short* Pout0, float oscale0,
                 const unsigned short* Ab1, const unsigned short* Bb1,
                 const float* bias1, unsigned short* Pout1, float oscale1,
                 int M, int N, int K,
                 size_t planeA, size_t planeB, size_t planeO)
{
    const unsigned short* Ab = Ab0;
    const unsigned short* Bb = Bb0;
    const float* biasp = bias0;
    unsigned short* Pout = Pout0;
    float oscale = oscale0;
    if constexpr (DUAL) {
        if (blockIdx.z) { Ab = Ab1; Bb = Bb1; biasp = bias1; Pout = Pout1; oscale = oscale1; }
    }

    // T1 chunked XCD swizzle (bijective since nwg = 16*32 = 512, 512%8==0)
    const int nbx = gridDim.x;
    const int nwg = nbx * gridDim.y;          // 512
    int bid = blockIdx.y * nbx + blockIdx.x;
    bid = (bid & 7) * (nwg >> 3) + (bid >> 3);
    const int m0 = (bid / nbx) * 128;
    const int n0 = (bid % nbx) * 64;

    // rows 0..127 = A-tile, rows 128..191 = B-tile
    __shared__ unsigned short S[2][NS][192][32];

    const int t = threadIdx.x;
    const int w = t >> 6, l = t & 63, g = l >> 4, j = l & 15;
    const int wm = w >> 1;          // 0..1  (M direction, 64 rows each)
    const int wn = w & 1;           // 0..1  (N direction, 32 cols each)

    f32x4 facc[8];
    f32x4 zacc[8];
    f32x4 macc[8];
    #pragma unroll
    for (int f = 0; f < 8; ++f) {
        facc[f] = (f32x4){0.f, 0.f, 0.f, 0.f};
        zacc[f] = (f32x4){0.f, 0.f, 0.f, 0.f};
        macc[f] = (f32x4){0.f, 0.f, 0.f, 0.f};
    }

    // staging geometry: wave w stages rows [w*16, w*16+16) of each 64-row
    // chunk; lane -> row l>>2, source col-granule (l&3) ^ ((l>>3)&3)
    // (pre-swizzled global source; LDS dest linear per gload_lds rule).
    const int stgrow = w * 16 + (l >> 2);
    const int stgcol = ((l & 3) ^ ((l >> 3) & 3)) * 8;
    const unsigned short* gA = Ab + (size_t)(m0 + stgrow) * K + stgcol;
    const unsigned short* gB = Bb + (size_t)(n0 + stgrow) * K + stgcol;

    auto stage = [&](int buf, int k0) {
        #pragma unroll
        for (int p = 0; p < NS; ++p) {
            gload16(gA + (size_t)p * planeA + k0,                  &S[buf][p][w * 16][0]);
            gload16(gA + (size_t)p * planeA + (size_t)64 * K + k0, &S[buf][p][64 + w * 16][0]);
            gload16(gB + (size_t)p * planeB + k0,                  &S[buf][p][128 + w * 16][0]);
        }
    };

    // swizzled fragment column (elements): matches the staging swizzle
    const int gs8 = (g ^ ((j >> 1) & 3)) * 8;

    stage(0, 0);
    const int NT = K / 32;
    for (int kt = 0; kt < NT; ++kt) {
        const int cur = kt & 1;
        if (kt + 1 < NT) {
            stage(cur ^ 1, (kt + 1) * 32);   // issue next tile: stays in flight
            if constexpr (NS == 2) asm volatile("s_waitcnt vmcnt(6)" ::: "memory");
            else                   asm volatile("s_waitcnt vmcnt(3)" ::: "memory");
        } else {
            asm volatile("s_waitcnt vmcnt(0)" ::: "memory");
        }
        __builtin_amdgcn_sched_barrier(0);
        __builtin_amdgcn_s_barrier();        // buf[cur] ready on all waves
        __builtin_amdgcn_sched_barrier(0);

        if constexpr (NS == 1) {
            s16x8 a[4];
            #pragma unroll
            for (int mi = 0; mi < 4; ++mi)
                a[mi] = *(const s16x8*)&S[cur][0][wm * 64 + mi * 16 + j][gs8];
            __builtin_amdgcn_s_setprio(1);
            #pragma unroll
            for (int ni = 0; ni < 2; ++ni) {
                const int nr = 128 + wn * 32 + ni * 16 + j;
                s16x8 b0 = *(const s16x8*)&S[cur][0][nr][gs8];
                #pragma unroll
                for (int mi = 0; mi < 4; ++mi) {
                    const int f = mi * 2 + ni;
                    facc[f] = __builtin_amdgcn_mfma_f32_16x16x32_bf16(a[mi], b0, facc[f], 0, 0, 0);
                }
            }
            __builtin_amdgcn_s_setprio(0);
        } else {
            f16x8 a0[4], a1[4];
            #pragma unroll
            for (int mi = 0; mi < 4; ++mi) {
                a0[mi] = *(const f16x8*)&S[cur][0][wm * 64 + mi * 16 + j][gs8];
                a1[mi] = *(const f16x8*)&S[cur][1][wm * 64 + mi * 16 + j][gs8];
            }
            __builtin_amdgcn_s_setprio(1);
            #pragma unroll
            for (int ni = 0; ni < 2; ++ni) {
                const int nr = 128 + wn * 32 + ni * 16 + j;
                f16x8 b0 = *(const f16x8*)&S[cur][0][nr][gs8];
                f16x8 b1 = *(const f16x8*)&S[cur][1][nr][gs8];
                #pragma unroll
                for (int mi = 0; mi < 4; ++mi) {
                    const int f = mi * 2 + ni;
                    zacc[f] = __builtin_amdgcn_mfma_f32_16x16x32_f16(a0[mi], b0, zacc[f], 0, 0, 0);
                    facc[f] = __builtin_amdgcn_mfma_f32_16x16x32_f16(a0[mi], b1, facc[f], 0, 0, 0);
                    facc[f] = __builtin_amdgcn_mfma_f32_16x16x32_f16(a1[mi], b0, facc[f], 0, 0, 0);
                }
            }
            __builtin_amdgcn_s_setprio(0);
            // hierarchical fold: f32 outer accumulate every 4 K-steps
            if ((kt & 3) == 3 || kt == NT - 1) {
                #pragma unroll
                for (int f = 0; f < 8; ++f) {
                    macc[f] += zacc[f];
                    zacc[f] = (f32x4){0.f, 0.f, 0.f, 0.f};
                }
            }
        }

        __builtin_amdgcn_sched_barrier(0);
        __builtin_amdgcn_s_barrier();        // all reads of buf[cur] done
        __builtin_amdgcn_sched_barrier(0);
    }

    #pragma unroll
    for (int ni = 0; ni < 2; ++ni) {
        const int col = n0 + wn * 32 + ni * 16 + j;
        const float bv = biasp[col];
        #pragma unroll
        for (int mi = 0; mi < 4; ++mi) {
            const int f = mi * 2 + ni;
            #pragma unroll
            for (int r = 0; r < 4; ++r) {
                const int row = m0 + wm * 64 + mi * 16 + 4 * g + r;
                float val;
                if (FOLD) val = (float)((double)macc[f][r] + (double)facc[f][r] * (1.0 / 2048.0) + (double)bv);
                else      val = facc[f][r] + bv;
                if (SPLITOUT) {
                    const int bq = row >> 10, s = row & 1023;
                    const int h  = col >> 6,  d = col & 63;
                    const size_t o = (((size_t)(bq * 16 + h)) * SEQ + s) * HDIM + d;
                    unsigned short u0, u1;
                    split2(val * oscale, u0, u1);
                    Pout[o] = u0; Pout[planeO + o] = u1;
                } else {
                    Cp[(size_t)row * N + col] = val;
                }
            }
        }
    }
}

// ---------------------------------------------------------------------------
// Fused attention, single-pass (UNCHANGED from R14): 128 q-rows/block, 8
// waves; fp16 split-2 QK^T (6 MFMAs/kb); T14 async-STAGE; Z-from-candidates
// (capture thr = rm-0.032, Z summed at finalize, online-Z deleted); exact
// fp64-cut prune; sparse PV gather. LDS ~58 KB -> 2 blocks/CU.
// ---------------------------------------------------------------------------
#define CAND 40
#define QROWS 128
__global__ __launch_bounds__(512, 4) void attn_k(const unsigned short* __restrict__ q3,
                                                 const unsigned short* __restrict__ k3,
                                                 const float* __restrict__ vf,
                                                 unsigned short* __restrict__ attnb,
                                                 size_t plane)
{
    __shared__ unsigned short Ks[2][64][72];   // 18.4 KB
    __shared__ int   ckey[QROWS][CAND];        // 20 KB
    __shared__ float csc[QROWS][CAND];         // 20 KB
    __shared__ int   ccnt[QROWS];
    __shared__ float zinv[QROWS];

    const int t  = threadIdx.x;
    const int w  = t >> 6, l = t & 63, g = l >> 4, j = l & 15;
    const int bh = blockIdx.x >> 3;     // 0..63
    const int qt = blockIdx.x & 7;      // 0..7 (128-row q groups)
    const int b  = bh >> 4, h = bh & 15;

    if (t < QROWS) ccnt[t] = 0;

    // A-frags for this wave's 16 q-rows (q pre-scaled 1/8 in planes)
    f16x8 aq[2][2];
    {
        const size_t qoff = ((size_t)bh * SEQ + qt * QROWS + w * 16 + j) * HDIM + g * 8;
        #pragma unroll
        for (int p = 0; p < 2; ++p)
            #pragma unroll
            for (int half = 0; half < 2; ++half)
                aq[p][half] = *(const f16x8*)(q3 + p * plane + qoff + half * 32);
    }

    // staging: 512 threads, each one uint4 (8 elems) per plane
    const int skey = t >> 3;            // staging key-local 0..63
    const int soff = (t & 7) * 8;       // element offset 0..56
    const unsigned short* ksrc = k3 + (size_t)bh * (SEQ * HDIM) + (size_t)skey * HDIM + soff;

    float rm[4];
    #pragma unroll
    for (int r = 0; r < 4; ++r) rm[r] = -INFINITY;

    // T14 prologue: chunk 0 loads in flight before the loop
    uint4 stg0 = *(const uint4*)(ksrc);
    uint4 stg1 = *(const uint4*)(ksrc + plane);

    for (int ch = 0; ch < 16; ++ch) {
        __syncthreads();                      // Ks free (prev readers done)
        *(uint4*)&Ks[0][skey][soff] = stg0;
        *(uint4*)&Ks[1][skey][soff] = stg1;
        __syncthreads();                      // Ks ready
        // issue next chunk's loads now; consumed at next iteration's ds_write
        if (ch + 1 < 16) {
            const unsigned short* s = ksrc + (ch + 1) * 4096;
            stg0 = *(const uint4*)(s);
            stg1 = *(const uint4*)(s + plane);
        }

        float sc[4][4];   // [kb][r]
        __builtin_amdgcn_s_setprio(1);
        #pragma unroll
        for (int kb = 0; kb < 4; ++kb) {
            f32x4 accM = {0.f,0.f,0.f,0.f};
            f32x4 accC0 = {0.f,0.f,0.f,0.f}, accC1 = {0.f,0.f,0.f,0.f};
            const int kr = kb * 16 + j;
            #pragma unroll
            for (int half = 0; half < 2; ++half) {
                f16x8 b0 = *(const f16x8*)&Ks[0][kr][half * 32 + g * 8];
                f16x8 b1 = *(const f16x8*)&Ks[1][kr][half * 32 + g * 8];
                accM  = __builtin_amdgcn_mfma_f32_16x16x32_f16(aq[0][half], b0, accM,  0, 0, 0);
                accC0 = __builtin_amdgcn_mfma_f32_16x16x32_f16(aq[0][half], b1, accC0, 0, 0, 0);
                accC1 = __builtin_amdgcn_mfma_f32_16x16x32_f16(aq[1][half], b0, accC1, 0, 0, 0);
            }
            #pragma unroll
            for (int r = 0; r < 4; ++r)
                sc[kb][r] = accM[r] + (accC0[r] + accC1[r]) * (1.0f / 2048.0f);
        }
        __builtin_amdgcn_s_setprio(0);

        // running max + candidate capture (no online Z)
        #pragma unroll
        for (int r = 0; r < 4; ++r) {
            float nmc = fmaxf(fmaxf(sc[0][r], sc[1][r]), fmaxf(sc[2][r], sc[3][r]));
            #pragma unroll
            for (int off = 1; off < 16; off <<= 1) nmc = fmaxf(nmc, __shfl_xor(nmc, off));
            // skip: all chunk scores < rm-0.033 < thr -> no capture possible,
            // and their Z terms are < e^-33 (sub-1e-14). Wave-uniform branch.
            if (__all(nmc <= rm[r] - 0.033f)) continue;
            rm[r] = fmaxf(nmc, rm[r]);
            const float thr = rm[r] - 0.032f;  // superset of survivors AND
                                               // of all Z-relevant terms
            #pragma unroll
            for (int kb = 0; kb < 4; ++kb) {
                if (sc[kb][r] >= thr) {
                    const int row = w * 16 + 4 * g + r;
                    const int pos = atomicAdd(&ccnt[row], 1);
                    if (pos < CAND) {
                        ckey[row][pos] = ch * 64 + kb * 16 + j;
                        csc[row][pos]  = sc[kb][r];
                    }
                }
            }
        }
    }
    __syncthreads();

    // finalize: Z from candidates (pass 1), exact fp64 cut, prune (pass 2)
    #pragma unroll
    for (int r = 0; r < 4; ++r) {
        if (j == r) {
            const int row = w * 16 + 4 * g + r;
            const int craw = ccnt[row];
            const int c = craw < CAND ? craw : CAND;
            float zm = 0.f;
            for (int i = 0; i < c; ++i)
                zm += __expf((csc[row][i] - rm[r]) * 1000.f);
            const double cut = (double)rm[r] + 0.001 * log(0.019 * (double)zm);
            int n = 0; float z2 = 0.f;
            for (int i = 0; i < c; ++i) {
                const float s = csc[row][i];
                if ((double)s >= cut) {
                    const float ev = __expf(s - rm[r]);
                    ckey[row][n] = ckey[row][i];
                    csc[row][n]  = ev;
                    z2 += ev; ++n;
                }
            }
            ccnt[row] = (craw > CAND) ? -1 : n;   // -1 = overflow sentinel
            zinv[row] = (n > 0) ? 1.f / z2 : 0.f;
        }
    }
    __syncthreads();

    // sparse PV gather (wave w handles its own 16 rows; lane l = dim).
    // 4-way load batching; fmac order matches the serial loop.
    const float* vbase = vf + (size_t)b * SEQ * DMODEL + h * HDIM + l;
    for (int i = 0; i < 16; ++i) {
        const int row = w * 16 + i;
        const int n = ccnt[row];
        float o = 0.f;
        if (n == 0) {
            // all masked -> uniform weights over all 1024 keys
            for (int kk = 0; kk < SEQ; ++kk) o += vbase[(size_t)kk * DMODEL];
            o *= (1.0f / 1024.0f);
        } else if (n < 0) {
            o = INFINITY;   // candidate overflow sentinel (visible failure)
        } else {
            const float inv = zinv[row];
            int i2 = 0;
            for (; i2 + 4 <= n; i2 += 4) {
                const float c0 = csc[row][i2 + 0], c1 = csc[row][i2 + 1];
                const float c2 = csc[row][i2 + 2], c3 = csc[row][i2 + 3];
                const float v0 = vbase[(size_t)ckey[row][i2 + 0] * DMODEL];
                const float v1 = vbase[(size_t)ckey[row][i2 + 1] * DMODEL];
                const float v2 = vbase[(size_t)ckey[row][i2 + 2] * DMODEL];
                const float v3 = vbase[(size_t)ckey[row][i2 + 3] * DMODEL];
                o += c0 * v0; o += c1 * v1; o += c2 * v2; o += c3 * v3;
            }
            for (; i2 < n; ++i2)
                o += csc[row][i2] * vbase[(size_t)ckey[row][i2] * DMODEL];
            o *= inv;
        }
        attnb[((size_t)b * SEQ + qt * QROWS + row) * DMODEL + h * HDIM + l] = f2bf(o);
    }
}

// ---------------------------------------------------------------------------
extern "C" void kernel_launch(void* const* d_in, const int* in_sizes, int n_in,
                              void* d_out, int out_size, void* d_ws, size_t ws_size,
                              hipStream_t stream) {
    const float* Q  = (const float*)d_in[0];
    const float* K  = (const float*)d_in[1];
    const float* V  = (const float*)d_in[2];
    const float* Wq = (const float*)d_in[3];
    const float* bq = (const float*)d_in[4];
    const float* Wk = (const float*)d_in[5];
    const float* bk = (const float*)d_in[6];
    const float* Wv = (const float*)d_in[7];
    const float* bv = (const float*)d_in[8];
    const float* Wo = (const float*)d_in[9];
    const float* bo = (const float*)d_in[10];

    const size_t PLANE  = (size_t)MROWS * DMODEL;     // 4 Mi elements
    const size_t WPLANE = (size_t)DMODEL * DMODEL;

    // Workspace layout (92 MiB total; <= round-0's 94 MiB footprint):
    unsigned short* R1 = (unsigned short*)d_ws;        // 2P: Q split -> attnb
    unsigned short* R2 = R1 + 2 * PLANE;               // 2P: K split
    unsigned short* W1 = R2 + 2 * PLANE;               // 1W: Wv bf16
    unsigned short* W2 = W1 + WPLANE;                  // 2W: Wq planes
    unsigned short* W3 = W2 + 2 * WPLANE;              // 2W: Wk planes
    unsigned short* W4 = W3 + 2 * WPLANE;              // 1W: Wo bf16
    unsigned short* q3 = W4 + WPLANE;                  // 2P
    unsigned short* k3 = q3 + 2 * PLANE;               // 2P (first P doubles
                                                       //  as V bf16 staging
                                                       //  until QK GEMM)
    float*          vf = (float*)(k3 + 2 * PLANE);     // PLANE f32
    unsigned short* attnb = R1;                        // reuse after QK GEMM
    unsigned short* Vb = k3;                           // V bf16 plane (temp)

    dim3 blk(256, 1, 1);
    const int nvec = (int)(PLANE / 8);
    dim3 gs3((nvec + 255) / 256, 3, 1);                // Q,K,V splits merged
    dim3 gw4(DMODEL / 64, DMODEL / 64, 4);             // all 4 wsplits merged
    dim3 gg(DMODEL / 64, MROWS / 128, 1);              // 512 blocks (NS=1)
    dim3 gg2(DMODEL / 64, MROWS / 128, 2);             // 1024 blocks (QK)

    // ---- 1: all input splits (Q->R1 fp16x2, K->R2 fp16x2, V->Vb bf16) ----
    prep_split<<<gs3, blk, 0, stream>>>(Q, R1, K, R2, V, Vb, nvec, PLANE);
    // ---- 2: all weight split+transposes ----
    prep_wsplit<<<gw4, blk, 0, stream>>>(Wq, W2, Wk, W3, Wv, W1, Wo, W4, WPLANE);
    // ---- 3: V projection (bf16) -> fp32 vf (consumes Vb before QK GEMM
    //         overwrites k3; stream-ordered) ----
    gemm_planes<1, false, false, false><<<gg, blk, 0, stream>>>(
        Vb, W1, bv, vf, nullptr, 1.0f,
        nullptr, nullptr, nullptr, nullptr, 0.f,
        MROWS, DMODEL, DMODEL, PLANE, WPLANE, PLANE);
    // ---- 4: merged Q+K projections -> q3, k3 ----
    gemm_planes<2, true, true, true><<<gg2, blk, 0, stream>>>(
        R1, W2, bq, nullptr, q3, 0.125f,
        R2, W3, bk, k3, 1.0f,
        MROWS, DMODEL, DMODEL, PLANE, WPLANE, PLANE);
    // ---- 5: fused masked attention -> bf16 attnb ----
    attn_k<<<dim3(64 * 8, 1, 1), dim3(512, 1, 1), 0, stream>>>(q3, k3, vf, attnb, PLANE);
    // ---- 6: O projection (bf16) -> fp32 d_out ----
    gemm_planes<1, false, false, false><<<gg, blk, 0, stream>>>(
        attnb, W4, bo, (float*)d_out, nullptr, 1.0f,
        nullptr, nullptr, nullptr, nullptr, 0.f,
        MROWS, DMODEL, DMODEL, PLANE, WPLANE, PLANE);
}